// Round 11
// baseline (310.992 us; speedup 1.0000x reference)
//
#include <hip/hip_runtime.h>
#include <cstdint>
#include <cstddef>
#include <utility>

typedef unsigned short u16;
typedef u16 u16x8 __attribute__((ext_vector_type(8)));
typedef u16 u16x4 __attribute__((ext_vector_type(4)));
typedef _Float16 f16x8 __attribute__((ext_vector_type(8)));
typedef float f32x4 __attribute__((ext_vector_type(4)));
typedef unsigned long long u64;

constexpr int B    = 4;
constexpr int CIN  = 64;
constexpr int COUT = 128;
constexpr int V    = 50000;
constexpr int KP1  = 7;
constexpr float EPS = 1e-5f;

constexpr int NTW  = (V + 31) / 32;      // 1563 wave-tiles (32 v each)
constexpr int NTPW = 1568;               // padded stride for P
constexpr int NT64 = (V + 63) / 64;      // 782 (final_mix tiles)

__device__ __forceinline__ u16 f2h(float f) {
    _Float16 h = (_Float16)f;
    return __builtin_bit_cast(u16, h);
}
__device__ __forceinline__ float h2f(u16 s) {
    return (float)__builtin_bit_cast(_Float16, s);
}

template<int... Is, typename F>
__device__ __forceinline__ void static_for_impl(F&& f, std::integer_sequence<int, Is...>) {
    (f(std::integral_constant<int, Is>{}), ...);
}
template<int N, typename F>
__device__ __forceinline__ void static_for(F&& f) {
    static_for_impl(f, std::make_integer_sequence<int, N>{});
}

// ---- W -> fragment-ordered fp16: wF[ch32][mfrag][lane][j] = W[o][r],
//      o = mfrag*16 + (lane&15), r = ch*32 + (lane>>4)*8 + j, r = k*C+c ----
template<int C>
__global__ __launch_bounds__(256) void prep_wf(const float* __restrict__ w,
                                               u16* __restrict__ wF) {
    constexpr int RCH = KP1 * C / 32;
    const int g = blockIdx.x * 256 + threadIdx.x;
    if (g >= RCH * 8 * 64) return;
    const int l  = g & 63;
    const int m  = (g >> 6) & 7;
    const int ch = g >> 9;
    const int k  = ch / (C / 32);
    const int c0 = (ch % (C / 32)) * 32;
    const int o  = m * 16 + (l & 15);
    u16x8 out;
#pragma unroll
    for (int j = 0; j < 8; ++j) {
        const int c = c0 + (l >> 4) * 8 + j;
        out[j] = f2h(w[((size_t)o * C + c) * KP1 + k]);
    }
    *(u16x8*)&wF[(size_t)g * 8] = out;
}

// ---- fe transpose: fe[b][c][v] (f32) -> feT[b][v][c] (f16) ----
__global__ __launch_bounds__(256) void transpose_fe(const float* __restrict__ fe,
                                                    u16* __restrict__ feT) {
    __shared__ u16 tile[32][33];
    const int t  = threadIdx.x;
    const int tx = t & 31, ty = t >> 5;           // 32 x 8
    const int v0 = blockIdx.x * 32;
    const int c0 = blockIdx.y * 32;
    const int b  = blockIdx.z;
#pragma unroll
    for (int p = 0; p < 4; ++p) {
        const int c = c0 + ty + p * 8;
        const int v = v0 + tx;
        if (v < V) tile[ty + p * 8][tx] = f2h(fe[((size_t)b * CIN + c) * V + v]);
    }
    __syncthreads();
#pragma unroll
    for (int p = 0; p < 4; ++p) {
        const int v = v0 + ty + p * 8;
        const int c = c0 + tx;
        if (v < V) feT[((size_t)b * V + v) * CIN + c] = tile[tx][ty + p * 8];
    }
}

// ---- MFMA gather-conv, 1-WAVE workgroups, ZERO barriers.
// Wave tile = 128o x 32v; 32-ch stages (NS = 14 or 28); private LDS dbuf.
// xin: vertex-major f16 [B][V][C]
// OUTL: 0 = vertex-major f16 [B][V][COUT]; 1 = channel-major f32
// Fuses instance-norm partials (sum, sumsq) -> P[(b*COUT+o)*NTPW + tw].
template<int C, int OUTL>
__global__ __launch_bounds__(64, 3) void conv_wave(const u16* __restrict__ xin,
                                                   const u16* __restrict__ wF,
                                                   const float* __restrict__ bias,
                                                   const int*  __restrict__ nbr,
                                                   void* __restrict__ out_,
                                                   float2* __restrict__ P) {
    constexpr int NS   = KP1 * C / 32;     // 14 (C=64) or 28 (C=128)
    constexpr int SPK  = C / 32;           // stages per k (2 or 4)
    constexpr int SMSK = SPK - 1;
    __shared__ __align__(16) u16 Xl[2][32][40];   // 5 KB, 80B rows (16B-aligned)

    const int l  = threadIdx.x;
    const int b  = blockIdx.x / NTW;
    const int tw = blockIdx.x % NTW;
    const int v0 = tw * 32;

    // staging role: row sv = l>>1 (0..31), 32B half h = l&1
    const int sv = l >> 1;
    const int h  = l & 1;
    int idxS[KP1];
    {
        const int vc = (v0 + sv < V) ? (v0 + sv) : 0;
        idxS[0] = vc;
#pragma unroll
        for (int k = 1; k < KP1; ++k)
            idxS[k] = nbr[((size_t)b * V + vc) * 6 + (k - 1)];
    }

    // consumer vertices
    int vn[2]; bool ok[2];
#pragma unroll
    for (int n = 0; n < 2; ++n) {
        vn[n] = v0 + n * 16 + (l & 15);
        ok[n] = vn[n] < V;
    }

    f32x4 acc[8][2];
#pragma unroll
    for (int m = 0; m < 8; ++m)
#pragma unroll
        for (int n = 0; n < 2; ++n) acc[m][n] = (f32x4)0.f;

    u16x8 g[2];       // 32 B gather payload per thread per stage
    auto gload = [&](auto SC) {
        constexpr int S  = decltype(SC)::value;
        constexpr int k_ = S / SPK;
        constexpr int c0 = (S & SMSK) * 32;
        const u16* p_ = &xin[((size_t)b * V + idxS[k_]) * C + c0 + h * 16];
        g[0] = *(const u16x8*)(p_);
        g[1] = *(const u16x8*)(p_ + 8);
    };
    auto store = [&](int bufi) {
        *(u16x8*)&Xl[bufi][sv][h * 16]     = g[0];
        *(u16x8*)&Xl[bufi][sv][h * 16 + 8] = g[1];
    };

    // prologue
    gload(std::integral_constant<int, 0>{});
    store(0);

    static_for<NS>([&](auto SC) {
        constexpr int s = decltype(SC)::value;
        // weight frags for THIS stage (issued first: vmcnt wait for af
        // does not force the newer gather to complete)
        f16x8 af[8];
#pragma unroll
        for (int m = 0; m < 8; ++m)
            af[m] = *(const f16x8*)&wF[(((size_t)s * 8 + m) * 64 + l) * 8];
        // gather for next stage
        if constexpr (s + 1 < NS) gload(std::integral_constant<int, s + 1>{});
        // B frags from current buffer
        f16x8 bf[2];
#pragma unroll
        for (int n = 0; n < 2; ++n)
            bf[n] = *(const f16x8*)&Xl[s & 1][n * 16 + (l & 15)][(l >> 4) * 8];
        // 16 MFMA
#pragma unroll
        for (int m = 0; m < 8; ++m)
#pragma unroll
            for (int n = 0; n < 2; ++n)
                acc[m][n] = __builtin_amdgcn_mfma_f32_16x16x32_f16(af[m], bf[n],
                                                                   acc[m][n], 0, 0, 0);
        // publish next stage into other buffer (same-wave ds ordering only)
        if constexpr (s + 1 < NS) store((s + 1) & 1);
    });

    // D layout: o = m*16 + (l>>4)*4 + q ; v = vn[n]
    if constexpr (OUTL == 0) {
        u16* po = (u16*)out_;
#pragma unroll
        for (int n = 0; n < 2; ++n) {
            if (ok[n]) {
#pragma unroll
                for (int m = 0; m < 8; ++m) {
                    const int o = m * 16 + ((l >> 4) << 2);
                    u16x4 pk;
#pragma unroll
                    for (int q = 0; q < 4; ++q) pk[q] = f2h(acc[m][n][q] + bias[o + q]);
                    __builtin_nontemporal_store(*(const u64*)&pk,
                        (u64*)&po[((size_t)b * V + vn[n]) * COUT + o]);
                }
            }
        }
    } else {
        float* po = (float*)out_;
#pragma unroll
        for (int m = 0; m < 8; ++m) {
            const int o = m * 16 + ((l >> 4) << 2);
#pragma unroll
            for (int q = 0; q < 4; ++q) {
                const float bq = bias[o + q];
#pragma unroll
                for (int n = 0; n < 2; ++n)
                    if (ok[n])
                        __builtin_nontemporal_store(acc[m][n][q] + bq,
                            &po[((size_t)(b * COUT + o + q)) * V + vn[n]]);
            }
        }
    }

    // fused instance-norm partials: wave-local, no LDS, no barrier
#pragma unroll
    for (int m = 0; m < 8; ++m) {
        const int o = m * 16 + ((l >> 4) << 2);
        float s[4], s2[4];
#pragma unroll
        for (int q = 0; q < 4; ++q) {
            const float bq = bias[o + q];
            float a = 0.f, aa = 0.f;
#pragma unroll
            for (int n = 0; n < 2; ++n) {
                if (ok[n]) {
                    const float val = acc[m][n][q] + bq;
                    a += val; aa += val * val;
                }
            }
            s[q] = a; s2[q] = aa;
        }
#pragma unroll
        for (int d = 1; d < 16; d <<= 1) {
#pragma unroll
            for (int q = 0; q < 4; ++q) {
                s[q]  += __shfl_xor(s[q],  d, 16);
                s2[q] += __shfl_xor(s2[q], d, 16);
            }
        }
        if ((l & 15) == 0) {
#pragma unroll
            for (int q = 0; q < 4; ++q)
                P[((size_t)b * COUT + o + q) * NTPW + tw] = make_float2(s[q], s2[q]);
        }
    }
}

// ---- finalize fused partials: S[row] = (mean, rsqrt(var+eps)) ----
__global__ __launch_bounds__(256) void finalize_fused(const float2* __restrict__ P,
                                                      float2* __restrict__ S) {
    const int row = blockIdx.x;       // B*COUT
    float s = 0.f, s2 = 0.f;
    for (int i = threadIdx.x; i < NTW; i += 256) {
        const float2 p = P[(size_t)row * NTPW + i];
        s += p.x; s2 += p.y;
    }
    __shared__ float2 red[256];
    red[threadIdx.x] = make_float2(s, s2);
    __syncthreads();
    for (int w = 128; w > 0; w >>= 1) {
        if (threadIdx.x < w) {
            red[threadIdx.x].x += red[threadIdx.x + w].x;
            red[threadIdx.x].y += red[threadIdx.x + w].y;
        }
        __syncthreads();
    }
    if (threadIdx.x == 0) {
        const float m = red[0].x / V;
        const float var = red[0].y / V - m * m;
        S[row] = make_float2(m, rsqrtf(var + EPS));
    }
}

// ---- normalize + relu in place, vertex-major f16 (ws) ----
__global__ __launch_bounds__(256) void norm1(u16* __restrict__ x,
                                             const float2* __restrict__ S) {
    const unsigned e = ((unsigned)blockIdx.x * 256u + threadIdx.x) * 8u;
    if (e >= (unsigned)B * V * COUT) return;
    const unsigned b  = e / ((unsigned)V * COUT);
    const unsigned o0 = e & 127u;
    u16x8 vv = *(u16x8*)&x[e];
#pragma unroll
    for (int j = 0; j < 8; ++j) {
        const float2 s = S[b * COUT + o0 + j];
        float f = (h2f(vv[j]) - s.x) * s.y;
        vv[j] = f2h(fmaxf(f, 0.f));
    }
    *(u16x8*)&x[e] = vv;
}

// ---- final (full tier): y2,x1 vertex-major f16 -> out channel-major f32 ----
__global__ __launch_bounds__(256) void final_mix2(const u16* __restrict__ y2,
                                                  const u16* __restrict__ x1,
                                                  const float2* __restrict__ S,
                                                  float* __restrict__ out) {
    __shared__ float ty[64][33], tx[64][33];
    const int t  = threadIdx.x;
    const int v0 = blockIdx.x * 64;
    const int o0 = blockIdx.y * 32;
    const int b  = blockIdx.z;
    const int jr = (t & 7) * 4;
    const int ir = t >> 3;             // 0..31
#pragma unroll
    for (int p = 0; p < 2; ++p) {
        const int i = ir + p * 32;
        const int v = v0 + i;
        if (v < V) {
            const size_t base = ((size_t)b * V + v) * COUT + o0 + jr;
            const u16x4 a = *(const u16x4*)&y2[base];
            const u16x4 c = *(const u16x4*)&x1[base];
#pragma unroll
            for (int q = 0; q < 4; ++q) {
                ty[i][jr + q] = h2f(a[q]);
                tx[i][jr + q] = h2f(c[q]);
            }
        }
    }
    __syncthreads();
    const int vl = t & 63, v = v0 + vl, oo0 = t >> 6;
    if (v < V) {
#pragma unroll
        for (int p = 0; p < 8; ++p) {
            const int oo = oo0 + p * 4;
            const int o  = o0 + oo;
            const float2 s = S[b * COUT + o];
            __builtin_nontemporal_store(
                fmaxf((ty[vl][oo] - s.x) * s.y + tx[vl][oo], 0.f),
                &out[((size_t)b * COUT + o) * V + v]);
        }
    }
}

// ---- final (fallback tier): y f32 CM in place; x1 f16 VM staged via LDS ----
__global__ __launch_bounds__(256) void final_mix(float* __restrict__ y,
                                                 const u16* __restrict__ x1,
                                                 const float2* __restrict__ S) {
    __shared__ float tile[64][33];
    const int t  = threadIdx.x;
    const int v0 = blockIdx.x * 64;
    const int o0 = blockIdx.y * 32;
    const int b  = blockIdx.z;
    const int j  = t & 31;
    const int i0 = t >> 5;
#pragma unroll
    for (int p = 0; p < 8; ++p) {
        const int i = i0 + p * 8;
        const int v = v0 + i;
        tile[i][j] = (v < V) ? h2f(x1[((size_t)b * V + v) * COUT + o0 + j]) : 0.f;
    }
    __syncthreads();
    const int vl  = t & 63;
    const int v   = v0 + vl;
    const int oo0 = t >> 6;
    if (v < V) {
#pragma unroll
        for (int p = 0; p < 8; ++p) {
            const int oo = oo0 + p * 4;
            const int o  = o0 + oo;
            const size_t idx = ((size_t)b * COUT + o) * V + v;
            const float2 s = S[b * COUT + o];
            const float f = (y[idx] - s.x) * s.y + tile[vl][oo];
            y[idx] = fmaxf(f, 0.f);
        }
    }
}

extern "C" void kernel_launch(void* const* d_in, const int* in_sizes, int n_in,
                              void* d_out, int out_size, void* d_ws, size_t ws_size,
                              hipStream_t stream) {
    const float* fe  = (const float*)d_in[0];
    const int*   nbr = (const int*)d_in[1];
    const float* w1  = (const float*)d_in[2];
    const float* b1  = (const float*)d_in[3];
    const float* w2  = (const float*)d_in[4];
    const float* b2  = (const float*)d_in[5];
    float* outf = (float*)d_out;
    char*  ws   = (char*)d_ws;

    constexpr size_t wF1_b = (size_t)(KP1 * CIN  / 32) * 8 * 64 * 8 * 2;  // 112 KB
    constexpr size_t wF2_b = (size_t)(KP1 * COUT / 32) * 8 * 64 * 8 * 2;  // 224 KB
    constexpr size_t S_b   = (size_t)B * COUT * 8;
    constexpr size_t Pf_b  = (size_t)B * COUT * NTPW * 8;  // 6.4 MB
    constexpr size_t x1_b  = (size_t)B * V * COUT * 2;     // 51.2 MB
    constexpr size_t y2_b  = (size_t)B * V * COUT * 2;     // 51.2 MB
    constexpr size_t feT_b = (size_t)B * V * CIN * 2;      // 25.6 MB
    const size_t base = wF1_b + wF2_b + 2 * S_b + Pf_b;

    // tiers: full (feT then y2 overlay in ext), t3 (feT in ext, f32-CM out),
    //        t4 (feT parked inside d_out until conv2 overwrites it)
    const bool full = (ws_size >= base + x1_b + y2_b);
    const bool t3   = (ws_size >= base + x1_b + feT_b);
    const bool t4   = (ws_size >= base + x1_b);
    if (!full && !t3 && !t4) return;

    size_t off = 0;
    u16*    wF1 = (u16*)(ws + off);    off += wF1_b;
    u16*    wF2 = (u16*)(ws + off);    off += wF2_b;
    float2* S1  = (float2*)(ws + off); off += S_b;
    float2* S2  = (float2*)(ws + off); off += S_b;
    float2* P   = (float2*)(ws + off); off += Pf_b;
    u16*    x1  = (u16*)(ws + off);    off += x1_b;
    u16*    ext = (u16*)(ws + off);    // feT and/or y2 region (full/t3)

    u16* feT = (full || t3) ? ext : (u16*)d_out;   // t4: park feT in d_out

    prep_wf<CIN> <<<(KP1 * CIN  / 32) * 8 * 64 / 256, 256, 0, stream>>>(w1, wF1);
    prep_wf<COUT><<<(KP1 * COUT / 32) * 8 * 64 / 256, 256, 0, stream>>>(w2, wF2);

    dim3 gt((V + 31) / 32, CIN / 32, B);
    transpose_fe<<<gt, 256, 0, stream>>>(fe, feT);

    conv_wave<CIN, 0><<<B * NTW, 64, 0, stream>>>(feT, wF1, b1, nbr, x1, P);
    finalize_fused<<<B * COUT, 256, 0, stream>>>(P, S1);
    norm1<<<(int)((size_t)B * V * COUT / 8 / 256), 256, 0, stream>>>(x1, S1);

    dim3 gf(NT64, COUT / 32, B);
    if (full) {
        u16* y2 = ext;   // overlays feT (dead after conv1)
        conv_wave<COUT, 0><<<B * NTW, 64, 0, stream>>>(x1, wF2, b2, nbr, y2, P);
        finalize_fused<<<B * COUT, 256, 0, stream>>>(P, S2);
        final_mix2<<<gf, 256, 0, stream>>>(y2, x1, S2, outf);
    } else {
        conv_wave<COUT, 1><<<B * NTW, 64, 0, stream>>>(x1, wF2, b2, nbr, outf, P);
        finalize_fused<<<B * COUT, 256, 0, stream>>>(P, S2);
        final_mix<<<gf, 256, 0, stream>>>(outf, x1, S2);
    }
}

// Round 13
// 276.592 us; speedup vs baseline: 1.1244x; 1.1244x over previous
//
#include <hip/hip_runtime.h>
#include <cstdint>
#include <cstddef>
#include <utility>

typedef unsigned short u16;
typedef u16 u16x8 __attribute__((ext_vector_type(8)));
typedef u16 u16x4 __attribute__((ext_vector_type(4)));
typedef _Float16 f16x8 __attribute__((ext_vector_type(8)));
typedef float f32x4 __attribute__((ext_vector_type(4)));
typedef unsigned long long u64;

constexpr int B    = 4;
constexpr int CIN  = 64;
constexpr int COUT = 128;
constexpr int V    = 50000;
constexpr int KP1  = 7;
constexpr float EPS = 1e-5f;

constexpr int BN   = 128;                // vertices per conv block
constexpr int NT   = (V + BN - 1) / BN;  // 391
constexpr int NTP  = 392;                // padded tiles (grid 4*392 % 8 == 0)
constexpr int NT64 = (V + 63) / 64;      // 782 (final_mix tiles)

__device__ __forceinline__ u16 f2h(float f) {
    _Float16 h = (_Float16)f;
    return __builtin_bit_cast(u16, h);
}
__device__ __forceinline__ float h2f(u16 s) {
    return (float)__builtin_bit_cast(_Float16, s);
}

// packed f16: a = max(a - m, 0)  (native _Float16 vector ops -> v_pk_*)
__device__ __forceinline__ void relusub8(u16x8& a, const u16x8& m) {
    f16x8 af = __builtin_bit_cast(f16x8, a);
    f16x8 mf = __builtin_bit_cast(f16x8, m);
    f16x8 r = af - mf;
#pragma unroll
    for (int j = 0; j < 8; ++j)
        r[j] = (r[j] > (_Float16)0.f) ? r[j] : (_Float16)0.f;
    a = __builtin_bit_cast(u16x8, r);
}

template<int... Is, typename F>
__device__ __forceinline__ void static_for_impl(F&& f, std::integer_sequence<int, Is...>) {
    (f(std::integral_constant<int, Is>{}), ...);
}
template<int N, typename F>
__device__ __forceinline__ void static_for(F&& f) {
    static_for_impl(f, std::make_integer_sequence<int, N>{});
}

// ---- W -> fragment-ordered fp16: wF[ch][mfrag][lane][j] = W[o][r],
//      o = mfrag*16 + (lane&15), r = ch*32 + (lane>>4)*8 + j, r = k*C+c ----
template<int C>
__global__ __launch_bounds__(256) void prep_wf(const float* __restrict__ w,
                                               u16* __restrict__ wF) {
    constexpr int RCH = KP1 * C / 32;
    const int g = blockIdx.x * 256 + threadIdx.x;
    if (g >= RCH * 8 * 64) return;
    const int l  = g & 63;
    const int m  = (g >> 6) & 7;
    const int ch = g >> 9;
    const int k  = ch / (C / 32);
    const int c0 = (ch % (C / 32)) * 32;
    const int o  = m * 16 + (l & 15);
    u16x8 out;
#pragma unroll
    for (int j = 0; j < 8; ++j) {
        const int c = c0 + (l >> 4) * 8 + j;
        out[j] = f2h(w[((size_t)o * C + c) * KP1 + k]);
    }
    *(u16x8*)&wF[(size_t)g * 8] = out;
}

// ---- W2 * inv_c (per batch): wF2[b][...] = W2[o][c][k] * S1[b][c].inv ----
__global__ __launch_bounds__(256) void prep_wf_inv(const float* __restrict__ w,
                                                   const float2* __restrict__ S1,
                                                   u16* __restrict__ wF) {
    constexpr int C = COUT;
    constexpr int RCH = KP1 * C / 32;      // 28
    const int g  = blockIdx.x * 256 + threadIdx.x;
    const int bb = blockIdx.y;
    if (g >= RCH * 8 * 64) return;
    const int l  = g & 63;
    const int m  = (g >> 6) & 7;
    const int ch = g >> 9;
    const int k  = ch / (C / 32);
    const int c0 = (ch % (C / 32)) * 32;
    const int o  = m * 16 + (l & 15);
    u16x8 out;
#pragma unroll
    for (int j = 0; j < 8; ++j) {
        const int c = c0 + (l >> 4) * 8 + j;
        out[j] = f2h(w[((size_t)o * C + c) * KP1 + k] * S1[bb * COUT + c].y);
    }
    *(u16x8*)&wF[(size_t)bb * RCH * 8 * 64 * 8 + (size_t)g * 8] = out;
}

// ---- fe transpose: fe[b][c][v] (f32) -> feT[b][v][c] (f16) ----
__global__ __launch_bounds__(256) void transpose_fe(const float* __restrict__ fe,
                                                    u16* __restrict__ feT) {
    __shared__ u16 tile[32][33];
    const int t  = threadIdx.x;
    const int tx = t & 31, ty = t >> 5;           // 32 x 8
    const int v0 = blockIdx.x * 32;
    const int c0 = blockIdx.y * 32;
    const int b  = blockIdx.z;
#pragma unroll
    for (int p = 0; p < 4; ++p) {
        const int c = c0 + ty + p * 8;
        const int v = v0 + tx;
        if (v < V) tile[ty + p * 8][tx] = f2h(fe[((size_t)b * CIN + c) * V + v]);
    }
    __syncthreads();
#pragma unroll
    for (int p = 0; p < 4; ++p) {
        const int v = v0 + ty + p * 8;
        const int c = c0 + tx;
        if (v < V) feT[((size_t)b * V + v) * CIN + c] = tile[tx][ty + p * 8];
    }
}

// ---- MFMA gather-conv: 64-ch stages, reg-staged LDS double-buffer,
//      counted-wait barriers, XCD batch-clustering swizzle.
// Grid = B * NTP (1568, %8==0). XCD pair {2b,2b+1} serves batch b.
// Block = 128o x 128v; waves 2x2, wave tile 64o x 64v; 32 MFMA per stage.
// xin: vertex-major f16 [B][V][C] (raw y1 for conv2)
// OUTL: 0 = vertex-major f16 [B][V][COUT]; 1 = channel-major f32
// NORM: 1 = apply relu(x - m) at stage-write time (m = mh[b][c], f16);
//       weights are per-batch (inv-folded).
// Fuses instance-norm partial stats (sum, sumsq) into P.
template<int C, int OUTL, int NORM>
__global__ __launch_bounds__(256, 4) void conv_mfma(const u16* __restrict__ xin,
                                                    const u16* __restrict__ wF,
                                                    const float* __restrict__ bias,
                                                    const int*  __restrict__ nbr,
                                                    const u16*  __restrict__ mh,
                                                    void* __restrict__ out_,
                                                    float2* __restrict__ P) {
    constexpr int NS = KP1 * C / 64;     // 7 or 14 stages (64 ch each)
    __shared__ __align__(16) u16 Xl[2][BN][72];   // 36.9 KB; 144B rows
    float2* SredF = (float2*)&Xl[0][0][0];        // overlay, used after K-loop

    const int i    = blockIdx.x;
    const int b    = (i & 7) >> 1;               // XCD pair -> batch
    const int tile = ((i >> 3) << 1) | (i & 1);  // 0..391 (391 = idle pad)
    const int v0   = tile * BN;
    const int t    = threadIdx.x;
    const int w    = t >> 6;
    const int l    = t & 63;
    const int wo   = (w & 1) * 64;       // wave o-offset
    const int wv   = (w >> 1) * 64;      // wave v-offset

    if constexpr (NORM)                  // per-batch inv-folded weights
        wF += (size_t)b * (KP1 * C / 32) * 8 * 64 * 8;

    // staging role: row sv = t>>1 (0..127), 64B half h = t&1
    const int sv = t >> 1;
    const int h  = t & 1;
    const int vS = v0 + sv;
    int idxS[KP1];
    {
        const int vc = (vS < V) ? vS : 0;
        idxS[0] = vc;
#pragma unroll
        for (int k = 1; k < KP1; ++k)
            idxS[k] = nbr[((size_t)b * V + vc) * 6 + (k - 1)];
    }

    // m (f16) for this thread's channel slice, both stage parities
    u16x8 mreg[2][4];
    if constexpr (NORM) {
        const u16* mp = mh + b * COUT;
#pragma unroll
        for (int sel = 0; sel < 2; ++sel)
#pragma unroll
            for (int j = 0; j < 4; ++j)
                mreg[sel][j] = *(const u16x8*)&mp[sel * 64 + h * 32 + j * 8];
    }

    // consumer vertices
    int vn[4]; bool ok[4];
#pragma unroll
    for (int n = 0; n < 4; ++n) {
        vn[n] = v0 + wv + n * 16 + (l & 15);
        ok[n] = vn[n] < V;
    }

    f32x4 acc[4][4];
#pragma unroll
    for (int m = 0; m < 4; ++m)
#pragma unroll
        for (int n = 0; n < 4; ++n) acc[m][n] = (f32x4)0.f;

    u16x8 g[4];       // gather regs: 64B per thread per stage
    f16x8 af[8];      // weight frags for current stage

    auto gload = [&](auto SC) {
        constexpr int S    = decltype(SC)::value;
        constexpr int k_   = (C == 64) ? S : (S >> 1);
        constexpr int off_ = (C == 64) ? 0 : (S & 1) * 64;
        const u16* p_ = &xin[((size_t)b * V + idxS[k_]) * C + off_ + h * 32];
#pragma unroll
        for (int j = 0; j < 4; ++j) g[j] = *(const u16x8*)(p_ + j * 8);
    };
    auto aload = [&](auto SC) {
        constexpr int S = decltype(SC)::value;
#pragma unroll
        for (int kc = 0; kc < 2; ++kc)
#pragma unroll
            for (int m = 0; m < 4; ++m)
                af[kc * 4 + m] =
                    *(const f16x8*)&wF[(((size_t)(2 * S + kc) * 8 + (wo >> 4) + m) * 64 + l) * 8];
    };
    auto store = [&](int bufi, auto SC) {
        if constexpr (NORM) {
            constexpr int sel = decltype(SC)::value & 1;
#pragma unroll
            for (int j = 0; j < 4; ++j) relusub8(g[j], mreg[sel][j]);
        }
#pragma unroll
        for (int j = 0; j < 4; ++j)
            *(u16x8*)&Xl[bufi][sv][h * 32 + j * 8] = g[j];
    };

    // prologue: stage0 -> buf0
    gload(std::integral_constant<int, 0>{});
    store(0, std::integral_constant<int, 0>{});
    asm volatile("s_waitcnt lgkmcnt(0)" ::: "memory");
    __builtin_amdgcn_s_barrier();

    static_for<NS>([&](auto SC) {
        constexpr int s = decltype(SC)::value;
        // 1. af for THIS stage first (any wait on af must not drain the gather)
        aload(SC);
        // 2. issue gather for stage s+1 (covered by bf reads + 32 MFMA)
        if constexpr (s + 1 < NS) gload(std::integral_constant<int, s + 1>{});
        // 3. bf reads from current buffer
        f16x8 bf[4][2];
#pragma unroll
        for (int n = 0; n < 4; ++n)
#pragma unroll
            for (int kc = 0; kc < 2; ++kc)
                bf[n][kc] = *(const f16x8*)&Xl[s & 1][wv + n * 16 + (l & 15)]
                                              [kc * 32 + (l >> 4) * 8];
        // 4. 32 MFMA
#pragma unroll
        for (int kc = 0; kc < 2; ++kc)
#pragma unroll
            for (int m = 0; m < 4; ++m)
#pragma unroll
                for (int n = 0; n < 4; ++n)
                    acc[m][n] = __builtin_amdgcn_mfma_f32_16x16x32_f16(af[kc * 4 + m],
                                                                       bf[n][kc],
                                                                       acc[m][n], 0, 0, 0);
        // 5. write next stage to the other buffer (vmcnt stall lands after MFMAs)
        if constexpr (s + 1 < NS) {
            __builtin_amdgcn_sched_barrier(0);
            store((s + 1) & 1, std::integral_constant<int, s + 1>{});
            asm volatile("s_waitcnt lgkmcnt(0)" ::: "memory");
            __builtin_amdgcn_s_barrier();
        }
    });

    // D layout: o = wo + m*16 + (l>>4)*4 + q ; v = vn[n]
    if constexpr (OUTL == 0) {
        u16* po = (u16*)out_;
#pragma unroll
        for (int n = 0; n < 4; ++n) {
            if (ok[n]) {
#pragma unroll
                for (int m = 0; m < 4; ++m) {
                    const int o = wo + m * 16 + ((l >> 4) << 2);
                    u16x4 pk;
#pragma unroll
                    for (int q = 0; q < 4; ++q) pk[q] = f2h(acc[m][n][q] + bias[o + q]);
                    __builtin_nontemporal_store(*(const u64*)&pk,
                        (u64*)&po[((size_t)b * V + vn[n]) * COUT + o]);
                }
            }
        }
    } else {
        float* po = (float*)out_;
#pragma unroll
        for (int m = 0; m < 4; ++m) {
            const int o = wo + m * 16 + ((l >> 4) << 2);
#pragma unroll
            for (int q = 0; q < 4; ++q) {
                const float bq = bias[o + q];
#pragma unroll
                for (int n = 0; n < 4; ++n)
                    if (ok[n])
                        __builtin_nontemporal_store(acc[m][n][q] + bq,
                            &po[((size_t)(b * COUT + o + q)) * V + vn[n]]);
            }
        }
    }

    // all LDS reads done before Sred overlay is written
    __syncthreads();

    // fused instance-norm partials
#pragma unroll
    for (int m = 0; m < 4; ++m) {
        const int o = wo + m * 16 + ((l >> 4) << 2);
        float s[4], s2[4];
#pragma unroll
        for (int q = 0; q < 4; ++q) {
            const float bq = bias[o + q];
            float a = 0.f, aa = 0.f;
#pragma unroll
            for (int n = 0; n < 4; ++n) {
                if (ok[n]) {
                    const float val = acc[m][n][q] + bq;
                    a += val; aa += val * val;
                }
            }
            s[q] = a; s2[q] = aa;
        }
#pragma unroll
        for (int d = 1; d < 16; d <<= 1) {
#pragma unroll
            for (int q = 0; q < 4; ++q) {
                s[q]  += __shfl_xor(s[q],  d, 16);
                s2[q] += __shfl_xor(s2[q], d, 16);
            }
        }
        if ((l & 15) == 0) {
#pragma unroll
            for (int q = 0; q < 4; ++q)
                SredF[w * COUT + o + q] = make_float2(s[q], s2[q]);
        }
    }
    __syncthreads();
    if (t < COUT) {
        const int wlo = t >> 6;            // o-half -> waves wlo and wlo+2
        const float2 a = SredF[wlo * COUT + t];
        const float2 c = SredF[(wlo + 2) * COUT + t];
        P[((size_t)b * COUT + t) * NTP + tile] = make_float2(a.x + c.x, a.y + c.y);
    }
}

// ---- finalize fused partials: S[row] = (mean, rsqrt(var+eps)); mh = f16 mean ----
__global__ __launch_bounds__(256) void finalize_fused(const float2* __restrict__ P,
                                                      float2* __restrict__ S,
                                                      u16* __restrict__ mh) {
    const int row = blockIdx.x;       // B*COUT
    float s = 0.f, s2 = 0.f;
    for (int i = threadIdx.x; i < NT; i += 256) {
        const float2 p = P[(size_t)row * NTP + i];
        s += p.x; s2 += p.y;
    }
    __shared__ float2 red[256];
    red[threadIdx.x] = make_float2(s, s2);
    __syncthreads();
    for (int w = 128; w > 0; w >>= 1) {
        if (threadIdx.x < w) {
            red[threadIdx.x].x += red[threadIdx.x + w].x;
            red[threadIdx.x].y += red[threadIdx.x + w].y;
        }
        __syncthreads();
    }
    if (threadIdx.x == 0) {
        const float m = red[0].x / V;
        const float var = red[0].y / V - m * m;
        S[row] = make_float2(m, rsqrtf(var + EPS));
        if (mh) mh[row] = f2h(m);
    }
}

// ---- final (full tier): y2,y1raw vertex-major f16 -> out channel-major f32 ----
// out = relu((y2 - m2)*inv2 + inv1*relu(y1 - m1))
__global__ __launch_bounds__(256) void final_mix2(const u16* __restrict__ y2,
                                                  const u16* __restrict__ y1,
                                                  const float2* __restrict__ S1,
                                                  const float2* __restrict__ S2,
                                                  float* __restrict__ out) {
    __shared__ float ty[64][33], tx[64][33];
    const int t  = threadIdx.x;
    const int v0 = blockIdx.x * 64;
    const int o0 = blockIdx.y * 32;
    const int b  = blockIdx.z;
    const int jr = (t & 7) * 4;
    const int ir = t >> 3;             // 0..31
#pragma unroll
    for (int p = 0; p < 2; ++p) {
        const int i = ir + p * 32;
        const int v = v0 + i;
        if (v < V) {
            const size_t base = ((size_t)b * V + v) * COUT + o0 + jr;
            const u16x4 a = *(const u16x4*)&y2[base];
            const u16x4 c = *(const u16x4*)&y1[base];
#pragma unroll
            for (int q = 0; q < 4; ++q) {
                const float2 s1 = S1[b * COUT + o0 + jr + q];
                ty[i][jr + q] = h2f(a[q]);
                tx[i][jr + q] = s1.y * fmaxf(h2f(c[q]) - s1.x, 0.f);
            }
        }
    }
    __syncthreads();
    const int vl = t & 63, v = v0 + vl, oo0 = t >> 6;
    if (v < V) {
#pragma unroll
        for (int p = 0; p < 8; ++p) {
            const int oo = oo0 + p * 4;
            const int o  = o0 + oo;
            const float2 s = S2[b * COUT + o];
            __builtin_nontemporal_store(
                fmaxf((ty[vl][oo] - s.x) * s.y + tx[vl][oo], 0.f),
                &out[((size_t)b * COUT + o) * V + v]);
        }
    }
}

// ---- final (fallback tier): y2 f32 CM in place; y1raw f16 VM staged via LDS ----
__global__ __launch_bounds__(256) void final_mix(float* __restrict__ y,
                                                 const u16* __restrict__ y1,
                                                 const float2* __restrict__ S1,
                                                 const float2* __restrict__ S2) {
    __shared__ float tile[64][33];
    const int t  = threadIdx.x;
    const int v0 = blockIdx.x * 64;
    const int o0 = blockIdx.y * 32;
    const int b  = blockIdx.z;
    const int j  = t & 31;
    const int i0 = t >> 5;
    const float2 s1 = S1[b * COUT + o0 + j];
#pragma unroll
    for (int p = 0; p < 8; ++p) {
        const int i = i0 + p * 8;
        const int v = v0 + i;
        tile[i][j] = (v < V)
            ? s1.y * fmaxf(h2f(y1[((size_t)b * V + v) * COUT + o0 + j]) - s1.x, 0.f)
            : 0.f;
    }
    __syncthreads();
    const int vl  = t & 63;
    const int v   = v0 + vl;
    const int oo0 = t >> 6;
    if (v < V) {
#pragma unroll
        for (int p = 0; p < 8; ++p) {
            const int oo = oo0 + p * 4;
            const int o  = o0 + oo;
            const size_t idx = ((size_t)b * COUT + o) * V + v;
            const float2 s = S2[b * COUT + o];
            const float f = (y[idx] - s.x) * s.y + tile[vl][oo];
            y[idx] = fmaxf(f, 0.f);
        }
    }
}

extern "C" void kernel_launch(void* const* d_in, const int* in_sizes, int n_in,
                              void* d_out, int out_size, void* d_ws, size_t ws_size,
                              hipStream_t stream) {
    const float* fe  = (const float*)d_in[0];
    const int*   nbr = (const int*)d_in[1];
    const float* w1  = (const float*)d_in[2];
    const float* b1  = (const float*)d_in[3];
    const float* w2  = (const float*)d_in[4];
    const float* b2  = (const float*)d_in[5];
    float* outf = (float*)d_out;
    char*  ws   = (char*)d_ws;

    constexpr size_t wF1_b = (size_t)(KP1 * CIN  / 32) * 8 * 64 * 8 * 2;      // 112 KB
    constexpr size_t wF2_b = (size_t)B * (KP1 * COUT / 32) * 8 * 64 * 8 * 2;  // 896 KB (x4)
    constexpr size_t S_b   = (size_t)B * COUT * 8;
    constexpr size_t mh_b  = ((size_t)B * COUT * 2 + 255) & ~255ull;
    constexpr size_t Pf_b  = (size_t)B * COUT * NTP * 8;  // 1.6 MB
    constexpr size_t x1_b  = (size_t)B * V * COUT * 2;    // 51.2 MB
    constexpr size_t y2_b  = (size_t)B * V * COUT * 2;    // 51.2 MB
    constexpr size_t feT_b = (size_t)B * V * CIN * 2;     // 25.6 MB
    const size_t base = wF1_b + wF2_b + 2 * S_b + mh_b + Pf_b;

    // tiers: full (feT then y2 overlay in ext), t3 (feT in ext, f32-CM out),
    //        t4 (feT parked inside d_out until conv2 overwrites it)
    const bool full = (ws_size >= base + x1_b + y2_b);
    const bool t3   = (ws_size >= base + x1_b + feT_b);
    const bool t4   = (ws_size >= base + x1_b);
    if (!full && !t3 && !t4) return;

    size_t off = 0;
    u16*    wF1 = (u16*)(ws + off);    off += wF1_b;
    u16*    wF2 = (u16*)(ws + off);    off += wF2_b;
    float2* S1  = (float2*)(ws + off); off += S_b;
    float2* S2  = (float2*)(ws + off); off += S_b;
    u16*    mh1 = (u16*)(ws + off);    off += mh_b;
    float2* P   = (float2*)(ws + off); off += Pf_b;
    u16*    x1  = (u16*)(ws + off);    off += x1_b;   // raw y1 (f16, VM)
    u16*    ext = (u16*)(ws + off);    // feT and/or y2 region (full/t3)

    u16* feT = (full || t3) ? ext : (u16*)d_out;   // t4: park feT in d_out

    prep_wf<CIN><<<(KP1 * CIN / 32) * 8 * 64 / 256, 256, 0, stream>>>(w1, wF1);

    dim3 gt((V + 31) / 32, CIN / 32, B);
    transpose_fe<<<gt, 256, 0, stream>>>(fe, feT);

    conv_mfma<CIN, 0, 0><<<B * NTP, 256, 0, stream>>>(feT, wF1, b1, nbr, nullptr, x1, P);
    finalize_fused<<<B * COUT, 256, 0, stream>>>(P, S1, mh1);

    // per-batch inv-folded conv2 weights (needs S1)
    dim3 gw((KP1 * COUT / 32) * 8 * 64 / 256, B);
    prep_wf_inv<<<gw, 256, 0, stream>>>(w2, S1, wF2);

    dim3 gf(NT64, COUT / 32, B);
    if (full) {
        u16* y2 = ext;   // overlays feT (dead after conv1)
        conv_mfma<COUT, 0, 1><<<B * NTP, 256, 0, stream>>>(x1, wF2, b2, nbr, mh1, y2, P);
        finalize_fused<<<B * COUT, 256, 0, stream>>>(P, S2, nullptr);
        final_mix2<<<gf, 256, 0, stream>>>(y2, x1, S1, S2, outf);
    } else {
        conv_mfma<COUT, 1, 1><<<B * NTP, 256, 0, stream>>>(x1, wF2, b2, nbr, mh1, outf, P);
        finalize_fused<<<B * COUT, 256, 0, stream>>>(P, S2, nullptr);
        final_mix<<<gf, 256, 0, stream>>>(outf, x1, S1, S2);
    }
}

// Round 14
// 254.233 us; speedup vs baseline: 1.2233x; 1.0879x over previous
//
#include <hip/hip_runtime.h>
#include <cstdint>
#include <cstddef>
#include <utility>

typedef unsigned short u16;
typedef u16 u16x8 __attribute__((ext_vector_type(8)));
typedef u16 u16x4 __attribute__((ext_vector_type(4)));
typedef _Float16 f16x8 __attribute__((ext_vector_type(8)));
typedef float f32x4 __attribute__((ext_vector_type(4)));

constexpr int B    = 4;
constexpr int CIN  = 64;
constexpr int COUT = 128;
constexpr int V    = 50000;
constexpr int KP1  = 7;
constexpr float EPS = 1e-5f;

constexpr int BN   = 128;                // vertices per conv block
constexpr int NT   = (V + BN - 1) / BN;  // 391
constexpr int NTP  = 392;                // padded tile stride for P
constexpr int NT64 = (V + 63) / 64;      // 782 (final_mix tiles)

__device__ __forceinline__ u16 f2h(float f) {
    _Float16 h = (_Float16)f;
    return __builtin_bit_cast(u16, h);
}
__device__ __forceinline__ float h2f(u16 s) {
    return (float)__builtin_bit_cast(_Float16, s);
}

// packed f16: a = max(a - m, 0)  (native _Float16 vector ops -> v_pk_*)
__device__ __forceinline__ void relusub8(u16x8& a, const u16x8& m) {
    f16x8 af = __builtin_bit_cast(f16x8, a);
    f16x8 mf = __builtin_bit_cast(f16x8, m);
    f16x8 r = af - mf;
#pragma unroll
    for (int j = 0; j < 8; ++j)
        r[j] = (r[j] > (_Float16)0.f) ? r[j] : (_Float16)0.f;
    a = __builtin_bit_cast(u16x8, r);
}

template<int... Is, typename F>
__device__ __forceinline__ void static_for_impl(F&& f, std::integer_sequence<int, Is...>) {
    (f(std::integral_constant<int, Is>{}), ...);
}
template<int N, typename F>
__device__ __forceinline__ void static_for(F&& f) {
    static_for_impl(f, std::make_integer_sequence<int, N>{});
}

// ---- W -> fragment-ordered fp16: wF[ch][mfrag][lane][j] = W[o][r],
//      o = mfrag*16 + (lane&15), r = ch*32 + (lane>>4)*8 + j, r = k*C+c ----
template<int C>
__global__ __launch_bounds__(256) void prep_wf(const float* __restrict__ w,
                                               u16* __restrict__ wF) {
    constexpr int RCH = KP1 * C / 32;
    const int g = blockIdx.x * 256 + threadIdx.x;
    if (g >= RCH * 8 * 64) return;
    const int l  = g & 63;
    const int m  = (g >> 6) & 7;
    const int ch = g >> 9;
    const int k  = ch / (C / 32);
    const int c0 = (ch % (C / 32)) * 32;
    const int o  = m * 16 + (l & 15);
    u16x8 out;
#pragma unroll
    for (int j = 0; j < 8; ++j) {
        const int c = c0 + (l >> 4) * 8 + j;
        out[j] = f2h(w[((size_t)o * C + c) * KP1 + k]);
    }
    *(u16x8*)&wF[(size_t)g * 8] = out;
}

// ---- W2 * inv_c (per batch): wF2[b][...] = W2[o][c][k] * S1[b][c].inv ----
__global__ __launch_bounds__(256) void prep_wf_inv(const float* __restrict__ w,
                                                   const float2* __restrict__ S1,
                                                   u16* __restrict__ wF) {
    constexpr int C = COUT;
    constexpr int RCH = KP1 * C / 32;      // 28
    const int g  = blockIdx.x * 256 + threadIdx.x;
    const int bb = blockIdx.y;
    if (g >= RCH * 8 * 64) return;
    const int l  = g & 63;
    const int m  = (g >> 6) & 7;
    const int ch = g >> 9;
    const int k  = ch / (C / 32);
    const int c0 = (ch % (C / 32)) * 32;
    const int o  = m * 16 + (l & 15);
    u16x8 out;
#pragma unroll
    for (int j = 0; j < 8; ++j) {
        const int c = c0 + (l >> 4) * 8 + j;
        out[j] = f2h(w[((size_t)o * C + c) * KP1 + k] * S1[bb * COUT + c].y);
    }
    *(u16x8*)&wF[(size_t)bb * RCH * 8 * 64 * 8 + (size_t)g * 8] = out;
}

// ---- fe transpose: fe[b][c][v] (f32) -> feT[b][v][c] (f16) ----
__global__ __launch_bounds__(256) void transpose_fe(const float* __restrict__ fe,
                                                    u16* __restrict__ feT) {
    __shared__ u16 tile[32][33];
    const int t  = threadIdx.x;
    const int tx = t & 31, ty = t >> 5;           // 32 x 8
    const int v0 = blockIdx.x * 32;
    const int c0 = blockIdx.y * 32;
    const int b  = blockIdx.z;
#pragma unroll
    for (int p = 0; p < 4; ++p) {
        const int c = c0 + ty + p * 8;
        const int v = v0 + tx;
        if (v < V) tile[ty + p * 8][tx] = f2h(fe[((size_t)b * CIN + c) * V + v]);
    }
    __syncthreads();
#pragma unroll
    for (int p = 0; p < 4; ++p) {
        const int v = v0 + ty + p * 8;
        const int c = c0 + tx;
        if (v < V) feT[((size_t)b * V + v) * CIN + c] = tile[tx][ty + p * 8];
    }
}

// ---- MFMA gather-conv: 64-ch stages; BOTH X and W staged in LDS
//      (reg-staged, double-buffered), counted-wait barriers.
// Grid = B * NT batch-major. Block = 128o x 128v; waves 2x2 (64o x 64v).
// xin: vertex-major f16 [B][V][C] (raw y1 for conv2)
// OUTL: 0 = vertex-major f16 [B][V][COUT]; 1 = channel-major f32
// NORM: 1 = apply relu(x - m) at stage-write time (m = mh[b][c], f16);
//       weights are per-batch (inv-folded).
// Fuses instance-norm partial stats (sum, sumsq) into P.
template<int C, int OUTL, int NORM>
__global__ __launch_bounds__(256, 2) void conv_mfma(const u16* __restrict__ xin,
                                                    const u16* __restrict__ wF,
                                                    const float* __restrict__ bias,
                                                    const int*  __restrict__ nbr,
                                                    const u16*  __restrict__ mh,
                                                    void* __restrict__ out_,
                                                    float2* __restrict__ P) {
    constexpr int NS = KP1 * C / 64;     // 7 or 14 stages (64 ch each)
    __shared__ __align__(16) u16 Xl[2][BN][72];   // 36.9 KB; 144B rows
    __shared__ __align__(16) u16 Wl[2][8192];     // 32 KB; 16 KB W-block per stage
    float2* SredF = (float2*)&Xl[0][0][0];        // overlay, used after K-loop

    const int t    = threadIdx.x;
    const int b    = blockIdx.x / NT;
    const int tile = blockIdx.x % NT;
    const int v0   = tile * BN;
    const int w    = t >> 6;
    const int l    = t & 63;
    const int wo   = (w & 1) * 64;       // wave o-offset
    const int wv   = (w >> 1) * 64;      // wave v-offset

    if constexpr (NORM)                  // per-batch inv-folded weights
        wF += (size_t)b * (KP1 * C / 32) * 8 * 64 * 8;

    // staging role: row sv = t>>1 (0..127), 64B half h = t&1
    const int sv = t >> 1;
    const int h  = t & 1;
    const int vS = v0 + sv;
    int idxS[KP1];
    {
        const int vc = (vS < V) ? vS : 0;
        idxS[0] = vc;
#pragma unroll
        for (int k = 1; k < KP1; ++k)
            idxS[k] = nbr[((size_t)b * V + vc) * 6 + (k - 1)];
    }

    // m (f16) for this thread's channel slice, both stage parities
    u16x8 mreg[2][4];
    if constexpr (NORM) {
        const u16* mp = mh + b * COUT;
#pragma unroll
        for (int sel = 0; sel < 2; ++sel)
#pragma unroll
            for (int j = 0; j < 4; ++j)
                mreg[sel][j] = *(const u16x8*)&mp[sel * 64 + h * 32 + j * 8];
    }

    // consumer vertices
    int vn[4]; bool ok[4];
#pragma unroll
    for (int n = 0; n < 4; ++n) {
        vn[n] = v0 + wv + n * 16 + (l & 15);
        ok[n] = vn[n] < V;
    }

    f32x4 acc[4][4];
#pragma unroll
    for (int m = 0; m < 4; ++m)
#pragma unroll
        for (int n = 0; n < 4; ++n) acc[m][n] = (f32x4)0.f;

    u16x8 g[4];       // X gather regs: 64B per thread per stage
    u16x8 wreg[4];    // W staging regs: 64B per thread per stage

    auto gload = [&](auto SC) {
        constexpr int S    = decltype(SC)::value;
        constexpr int k_   = (C == 64) ? S : (S >> 1);
        constexpr int off_ = (C == 64) ? 0 : (S & 1) * 64;
        const u16* p_ = &xin[((size_t)b * V + idxS[k_]) * C + off_ + h * 32];
#pragma unroll
        for (int j = 0; j < 4; ++j) g[j] = *(const u16x8*)(p_ + j * 8);
    };
    auto wgload = [&](auto SC) {
        constexpr int S = decltype(SC)::value;
        const u16* p_ = wF + (size_t)S * 8192 + t * 32;   // stage W-block contiguous
#pragma unroll
        for (int j = 0; j < 4; ++j) wreg[j] = *(const u16x8*)(p_ + j * 8);
    };
    auto store = [&](int bufi, auto SC) {
        if constexpr (NORM) {
            constexpr int sel = decltype(SC)::value & 1;
#pragma unroll
            for (int j = 0; j < 4; ++j) relusub8(g[j], mreg[sel][j]);
        }
#pragma unroll
        for (int j = 0; j < 4; ++j)
            *(u16x8*)&Xl[bufi][sv][h * 32 + j * 8] = g[j];
    };
    auto wstore = [&](int bufi) {
#pragma unroll
        for (int j = 0; j < 4; ++j)
            *(u16x8*)&Wl[bufi][t * 32 + j * 8] = wreg[j];
    };

    // prologue: stage0 -> buf0 (X and W)
    gload(std::integral_constant<int, 0>{});
    wgload(std::integral_constant<int, 0>{});
    store(0, std::integral_constant<int, 0>{});
    wstore(0);
    asm volatile("s_waitcnt lgkmcnt(0)" ::: "memory");
    __builtin_amdgcn_s_barrier();

    static_for<NS>([&](auto SC) {
        constexpr int s = decltype(SC)::value;
        // 1. af + bf ds_reads from current buffers
        f16x8 af[8];
#pragma unroll
        for (int kc = 0; kc < 2; ++kc)
#pragma unroll
            for (int m = 0; m < 4; ++m)
                af[kc * 4 + m] =
                    *(const f16x8*)&Wl[s & 1][((kc * 8 + (wo >> 4) + m) * 64 + l) * 8];
        f16x8 bf[4][2];
#pragma unroll
        for (int n = 0; n < 4; ++n)
#pragma unroll
            for (int kc = 0; kc < 2; ++kc)
                bf[n][kc] = *(const f16x8*)&Xl[s & 1][wv + n * 16 + (l & 15)]
                                              [kc * 32 + (l >> 4) * 8];
        // 2. issue next-stage global loads (covered by ds_reads + MFMAs)
        if constexpr (s + 1 < NS) {
            wgload(std::integral_constant<int, s + 1>{});
            gload(std::integral_constant<int, s + 1>{});
        }
        // 3. 32 MFMA
#pragma unroll
        for (int kc = 0; kc < 2; ++kc)
#pragma unroll
            for (int m = 0; m < 4; ++m)
#pragma unroll
                for (int n = 0; n < 4; ++n)
                    acc[m][n] = __builtin_amdgcn_mfma_f32_16x16x32_f16(af[kc * 4 + m],
                                                                       bf[n][kc],
                                                                       acc[m][n], 0, 0, 0);
        // 4. write next stage into other buffers (vmcnt stall lands after MFMAs)
        if constexpr (s + 1 < NS) {
            __builtin_amdgcn_sched_barrier(0);
            store((s + 1) & 1, std::integral_constant<int, s + 1>{});
            wstore((s + 1) & 1);
            asm volatile("s_waitcnt lgkmcnt(0)" ::: "memory");
            __builtin_amdgcn_s_barrier();
        }
    });

    // D layout: o = wo + m*16 + (l>>4)*4 + q ; v = vn[n]
    if constexpr (OUTL == 0) {
        u16* po = (u16*)out_;
#pragma unroll
        for (int n = 0; n < 4; ++n) {
            if (ok[n]) {
#pragma unroll
                for (int m = 0; m < 4; ++m) {
                    const int o = wo + m * 16 + ((l >> 4) << 2);
                    u16x4 pk;
#pragma unroll
                    for (int q = 0; q < 4; ++q) pk[q] = f2h(acc[m][n][q] + bias[o + q]);
                    *(u16x4*)&po[((size_t)b * V + vn[n]) * COUT + o] = pk;
                }
            }
        }
    } else {
        float* po = (float*)out_;
#pragma unroll
        for (int m = 0; m < 4; ++m) {
            const int o = wo + m * 16 + ((l >> 4) << 2);
#pragma unroll
            for (int q = 0; q < 4; ++q) {
                const float bq = bias[o + q];
#pragma unroll
                for (int n = 0; n < 4; ++n)
                    if (ok[n]) po[((size_t)(b * COUT + o + q)) * V + vn[n]] = acc[m][n][q] + bq;
            }
        }
    }

    // all LDS reads done before Sred overlay is written
    __syncthreads();

    // fused instance-norm partials
#pragma unroll
    for (int m = 0; m < 4; ++m) {
        const int o = wo + m * 16 + ((l >> 4) << 2);
        float s[4], s2[4];
#pragma unroll
        for (int q = 0; q < 4; ++q) {
            const float bq = bias[o + q];
            float a = 0.f, aa = 0.f;
#pragma unroll
            for (int n = 0; n < 4; ++n) {
                if (ok[n]) {
                    const float val = acc[m][n][q] + bq;
                    a += val; aa += val * val;
                }
            }
            s[q] = a; s2[q] = aa;
        }
#pragma unroll
        for (int d = 1; d < 16; d <<= 1) {
#pragma unroll
            for (int q = 0; q < 4; ++q) {
                s[q]  += __shfl_xor(s[q],  d, 16);
                s2[q] += __shfl_xor(s2[q], d, 16);
            }
        }
        if ((l & 15) == 0) {
#pragma unroll
            for (int q = 0; q < 4; ++q)
                SredF[w * COUT + o + q] = make_float2(s[q], s2[q]);
        }
    }
    __syncthreads();
    if (t < COUT) {
        const int wlo = t >> 6;            // o-half -> waves wlo and wlo+2
        const float2 a = SredF[wlo * COUT + t];
        const float2 c = SredF[(wlo + 2) * COUT + t];
        P[((size_t)b * COUT + t) * NTP + tile] = make_float2(a.x + c.x, a.y + c.y);
    }
}

// ---- finalize fused partials: S[row] = (mean, rsqrt(var+eps)); mh = f16 mean ----
__global__ __launch_bounds__(256) void finalize_fused(const float2* __restrict__ P,
                                                      float2* __restrict__ S,
                                                      u16* __restrict__ mh) {
    const int row = blockIdx.x;       // B*COUT
    float s = 0.f, s2 = 0.f;
    for (int i = threadIdx.x; i < NT; i += 256) {
        const float2 p = P[(size_t)row * NTP + i];
        s += p.x; s2 += p.y;
    }
    __shared__ float2 red[256];
    red[threadIdx.x] = make_float2(s, s2);
    __syncthreads();
    for (int w = 128; w > 0; w >>= 1) {
        if (threadIdx.x < w) {
            red[threadIdx.x].x += red[threadIdx.x + w].x;
            red[threadIdx.x].y += red[threadIdx.x + w].y;
        }
        __syncthreads();
    }
    if (threadIdx.x == 0) {
        const float m = red[0].x / V;
        const float var = red[0].y / V - m * m;
        S[row] = make_float2(m, rsqrtf(var + EPS));
        if (mh) mh[row] = f2h(m);
    }
}

// ---- final (full tier): y2,y1raw vertex-major f16 -> out channel-major f32 ----
// out = relu((y2 - m2)*inv2 + inv1*relu(y1 - m1))
__global__ __launch_bounds__(256) void final_mix2(const u16* __restrict__ y2,
                                                  const u16* __restrict__ y1,
                                                  const float2* __restrict__ S1,
                                                  const float2* __restrict__ S2,
                                                  float* __restrict__ out) {
    __shared__ float ty[64][33], tx[64][33];
    const int t  = threadIdx.x;
    const int v0 = blockIdx.x * 64;
    const int o0 = blockIdx.y * 32;
    const int b  = blockIdx.z;
    const int jr = (t & 7) * 4;
    const int ir = t >> 3;             // 0..31
#pragma unroll
    for (int p = 0; p < 2; ++p) {
        const int i = ir + p * 32;
        const int v = v0 + i;
        if (v < V) {
            const size_t base = ((size_t)b * V + v) * COUT + o0 + jr;
            const u16x4 a = *(const u16x4*)&y2[base];
            const u16x4 c = *(const u16x4*)&y1[base];
#pragma unroll
            for (int q = 0; q < 4; ++q) {
                const float2 s1 = S1[b * COUT + o0 + jr + q];
                ty[i][jr + q] = h2f(a[q]);
                tx[i][jr + q] = s1.y * fmaxf(h2f(c[q]) - s1.x, 0.f);
            }
        }
    }
    __syncthreads();
    const int vl = t & 63, v = v0 + vl, oo0 = t >> 6;
    if (v < V) {
#pragma unroll
        for (int p = 0; p < 8; ++p) {
            const int oo = oo0 + p * 4;
            const int o  = o0 + oo;
            const float2 s = S2[b * COUT + o];
            out[((size_t)b * COUT + o) * V + v] =
                fmaxf((ty[vl][oo] - s.x) * s.y + tx[vl][oo], 0.f);
        }
    }
}

// ---- final (fallback tier): y2 f32 CM in place; y1raw f16 VM staged via LDS ----
__global__ __launch_bounds__(256) void final_mix(float* __restrict__ y,
                                                 const u16* __restrict__ y1,
                                                 const float2* __restrict__ S1,
                                                 const float2* __restrict__ S2) {
    __shared__ float tile[64][33];
    const int t  = threadIdx.x;
    const int v0 = blockIdx.x * 64;
    const int o0 = blockIdx.y * 32;
    const int b  = blockIdx.z;
    const int j  = t & 31;
    const int i0 = t >> 5;
    const float2 s1 = S1[b * COUT + o0 + j];
#pragma unroll
    for (int p = 0; p < 8; ++p) {
        const int i = i0 + p * 8;
        const int v = v0 + i;
        tile[i][j] = (v < V)
            ? s1.y * fmaxf(h2f(y1[((size_t)b * V + v) * COUT + o0 + j]) - s1.x, 0.f)
            : 0.f;
    }
    __syncthreads();
    const int vl  = t & 63;
    const int v   = v0 + vl;
    const int oo0 = t >> 6;
    if (v < V) {
#pragma unroll
        for (int p = 0; p < 8; ++p) {
            const int oo = oo0 + p * 4;
            const int o  = o0 + oo;
            const size_t idx = ((size_t)b * COUT + o) * V + v;
            const float2 s = S2[b * COUT + o];
            const float f = (y[idx] - s.x) * s.y + tile[vl][oo];
            y[idx] = fmaxf(f, 0.f);
        }
    }
}

extern "C" void kernel_launch(void* const* d_in, const int* in_sizes, int n_in,
                              void* d_out, int out_size, void* d_ws, size_t ws_size,
                              hipStream_t stream) {
    const float* fe  = (const float*)d_in[0];
    const int*   nbr = (const int*)d_in[1];
    const float* w1  = (const float*)d_in[2];
    const float* b1  = (const float*)d_in[3];
    const float* w2  = (const float*)d_in[4];
    const float* b2  = (const float*)d_in[5];
    float* outf = (float*)d_out;
    char*  ws   = (char*)d_ws;

    constexpr size_t wF1_b = (size_t)(KP1 * CIN  / 32) * 8 * 64 * 8 * 2;      // 112 KB
    constexpr size_t wF2_b = (size_t)B * (KP1 * COUT / 32) * 8 * 64 * 8 * 2;  // 896 KB (x4)
    constexpr size_t S_b   = (size_t)B * COUT * 8;
    constexpr size_t mh_b  = ((size_t)B * COUT * 2 + 255) & ~255ull;
    constexpr size_t Pf_b  = (size_t)B * COUT * NTP * 8;  // 1.6 MB
    constexpr size_t x1_b  = (size_t)B * V * COUT * 2;    // 51.2 MB
    constexpr size_t y2_b  = (size_t)B * V * COUT * 2;    // 51.2 MB
    constexpr size_t feT_b = (size_t)B * V * CIN * 2;     // 25.6 MB
    const size_t base = wF1_b + wF2_b + 2 * S_b + mh_b + Pf_b;

    // tiers: full (feT then y2 overlay in ext), t3 (feT in ext, f32-CM out),
    //        t4 (feT parked inside d_out until conv2 overwrites it)
    const bool full = (ws_size >= base + x1_b + y2_b);
    const bool t3   = (ws_size >= base + x1_b + feT_b);
    const bool t4   = (ws_size >= base + x1_b);
    if (!full && !t3 && !t4) return;

    size_t off = 0;
    u16*    wF1 = (u16*)(ws + off);    off += wF1_b;
    u16*    wF2 = (u16*)(ws + off);    off += wF2_b;
    float2* S1  = (float2*)(ws + off); off += S_b;
    float2* S2  = (float2*)(ws + off); off += S_b;
    u16*    mh1 = (u16*)(ws + off);    off += mh_b;
    float2* P   = (float2*)(ws + off); off += Pf_b;
    u16*    x1  = (u16*)(ws + off);    off += x1_b;   // raw y1 (f16, VM)
    u16*    ext = (u16*)(ws + off);    // feT and/or y2 region (full/t3)

    u16* feT = (full || t3) ? ext : (u16*)d_out;   // t4: park feT in d_out

    prep_wf<CIN><<<(KP1 * CIN / 32) * 8 * 64 / 256, 256, 0, stream>>>(w1, wF1);

    dim3 gt((V + 31) / 32, CIN / 32, B);
    transpose_fe<<<gt, 256, 0, stream>>>(fe, feT);

    conv_mfma<CIN, 0, 0><<<B * NT, 256, 0, stream>>>(feT, wF1, b1, nbr, nullptr, x1, P);
    finalize_fused<<<B * COUT, 256, 0, stream>>>(P, S1, mh1);

    // per-batch inv-folded conv2 weights (needs S1)
    dim3 gw((KP1 * COUT / 32) * 8 * 64 / 256, B);
    prep_wf_inv<<<gw, 256, 0, stream>>>(w2, S1, wF2);

    dim3 gf(NT64, COUT / 32, B);
    if (full) {
        u16* y2 = ext;   // overlays feT (dead after conv1)
        conv_mfma<COUT, 0, 1><<<B * NT, 256, 0, stream>>>(x1, wF2, b2, nbr, mh1, y2, P);
        finalize_fused<<<B * COUT, 256, 0, stream>>>(P, S2, nullptr);
        final_mix2<<<gf, 256, 0, stream>>>(y2, x1, S1, S2, outf);
    } else {
        conv_mfma<COUT, 1, 1><<<B * NT, 256, 0, stream>>>(x1, wF2, b2, nbr, mh1, outf, P);
        finalize_fused<<<B * COUT, 256, 0, stream>>>(P, S2, nullptr);
        final_mix<<<gf, 256, 0, stream>>>(outf, x1, S1, S2);
    }
}

// Round 15
// 224.258 us; speedup vs baseline: 1.3868x; 1.1337x over previous
//
#include <hip/hip_runtime.h>
#include <cstdint>
#include <cstddef>
#include <utility>

typedef unsigned short u16;
typedef u16 u16x8 __attribute__((ext_vector_type(8)));
typedef u16 u16x4 __attribute__((ext_vector_type(4)));
typedef _Float16 f16x8 __attribute__((ext_vector_type(8)));
typedef float f32x4 __attribute__((ext_vector_type(4)));

constexpr int B    = 4;
constexpr int CIN  = 64;
constexpr int COUT = 128;
constexpr int V    = 50000;
constexpr int KP1  = 7;
constexpr float EPS = 1e-5f;

constexpr int BN   = 128;                // vertices per conv block
constexpr int NT   = (V + BN - 1) / BN;  // 391
constexpr int NTP  = 392;                // padded tile stride for P
constexpr int NT64 = (V + 63) / 64;      // 782 (final_mix tiles)

__device__ __forceinline__ u16 f2h(float f) {
    _Float16 h = (_Float16)f;
    return __builtin_bit_cast(u16, h);
}
__device__ __forceinline__ float h2f(u16 s) {
    return (float)__builtin_bit_cast(_Float16, s);
}

// packed f16: a = max(a - m, 0)  (native _Float16 vector ops -> v_pk_*)
__device__ __forceinline__ void relusub8(u16x8& a, const u16x8& m) {
    f16x8 af = __builtin_bit_cast(f16x8, a);
    f16x8 mf = __builtin_bit_cast(f16x8, m);
    f16x8 r = af - mf;
#pragma unroll
    for (int j = 0; j < 8; ++j)
        r[j] = (r[j] > (_Float16)0.f) ? r[j] : (_Float16)0.f;
    a = __builtin_bit_cast(u16x8, r);
}

template<int... Is, typename F>
__device__ __forceinline__ void static_for_impl(F&& f, std::integer_sequence<int, Is...>) {
    (f(std::integral_constant<int, Is>{}), ...);
}
template<int N, typename F>
__device__ __forceinline__ void static_for(F&& f) {
    static_for_impl(f, std::make_integer_sequence<int, N>{});
}

// ---- W -> fragment-ordered fp16: wF[ch][mfrag][lane][j] = W[o][r],
//      o = mfrag*16 + (lane&15), r = ch*32 + (lane>>4)*8 + j, r = k*C+c ----
template<int C>
__global__ __launch_bounds__(256) void prep_wf(const float* __restrict__ w,
                                               u16* __restrict__ wF) {
    constexpr int RCH = KP1 * C / 32;
    const int g = blockIdx.x * 256 + threadIdx.x;
    if (g >= RCH * 8 * 64) return;
    const int l  = g & 63;
    const int m  = (g >> 6) & 7;
    const int ch = g >> 9;
    const int k  = ch / (C / 32);
    const int c0 = (ch % (C / 32)) * 32;
    const int o  = m * 16 + (l & 15);
    u16x8 out;
#pragma unroll
    for (int j = 0; j < 8; ++j) {
        const int c = c0 + (l >> 4) * 8 + j;
        out[j] = f2h(w[((size_t)o * C + c) * KP1 + k]);
    }
    *(u16x8*)&wF[(size_t)g * 8] = out;
}

// ---- W2 * inv_c (per batch): wF2[b][...] = W2[o][c][k] * S1[b][c].inv ----
__global__ __launch_bounds__(256) void prep_wf_inv(const float* __restrict__ w,
                                                   const float2* __restrict__ S1,
                                                   u16* __restrict__ wF) {
    constexpr int C = COUT;
    constexpr int RCH = KP1 * C / 32;      // 28
    const int g  = blockIdx.x * 256 + threadIdx.x;
    const int bb = blockIdx.y;
    if (g >= RCH * 8 * 64) return;
    const int l  = g & 63;
    const int m  = (g >> 6) & 7;
    const int ch = g >> 9;
    const int k  = ch / (C / 32);
    const int c0 = (ch % (C / 32)) * 32;
    const int o  = m * 16 + (l & 15);
    u16x8 out;
#pragma unroll
    for (int j = 0; j < 8; ++j) {
        const int c = c0 + (l >> 4) * 8 + j;
        out[j] = f2h(w[((size_t)o * C + c) * KP1 + k] * S1[bb * COUT + c].y);
    }
    *(u16x8*)&wF[(size_t)bb * RCH * 8 * 64 * 8 + (size_t)g * 8] = out;
}

// ---- fe transpose: fe[b][c][v] (f32) -> feT[b][v][c] (f16) ----
__global__ __launch_bounds__(256) void transpose_fe(const float* __restrict__ fe,
                                                    u16* __restrict__ feT) {
    __shared__ u16 tile[32][33];
    const int t  = threadIdx.x;
    const int tx = t & 31, ty = t >> 5;           // 32 x 8
    const int v0 = blockIdx.x * 32;
    const int c0 = blockIdx.y * 32;
    const int b  = blockIdx.z;
#pragma unroll
    for (int p = 0; p < 4; ++p) {
        const int c = c0 + ty + p * 8;
        const int v = v0 + tx;
        if (v < V) tile[ty + p * 8][tx] = f2h(fe[((size_t)b * CIN + c) * V + v]);
    }
    __syncthreads();
#pragma unroll
    for (int p = 0; p < 4; ++p) {
        const int v = v0 + ty + p * 8;
        const int c = c0 + tx;
        if (v < V) feT[((size_t)b * V + v) * CIN + c] = tile[tx][ty + p * 8];
    }
}

// ---- MFMA gather-conv (round-8 structure): 64-channel stages, 2 LDS buffers,
//      reg-staged depth-2 gather pipeline, counted-wait barriers.
// Block = 128o x 128v; waves 2x2, wave tile 64o x 64v; 32 MFMA per barrier.
// xin: vertex-major f16 [B][V][C] (raw y1 for conv2)
// OUTL: 0 = vertex-major f16 [B][V][COUT]; 1 = channel-major f32
// NORM: 1 = apply relu(x - m) at stage-write time (m = mh[b][c], f16);
//       weights are per-batch (inv-folded).
// Fuses instance-norm partial stats (sum, sumsq) into P.
template<int C, int OUTL, int NORM>
__global__ __launch_bounds__(256, 2) void conv_mfma(const u16* __restrict__ xin,
                                                    const u16* __restrict__ wF,
                                                    const float* __restrict__ bias,
                                                    const int*  __restrict__ nbr,
                                                    const u16*  __restrict__ mh,
                                                    void* __restrict__ out_,
                                                    float2* __restrict__ P) {
    constexpr int NS = KP1 * C / 64;     // 7 or 14 stages (64 ch each)
    __shared__ __align__(16) u16 Xl[2][BN][72];   // 36.9 KB; 144B rows
    __shared__ float2 Sred[4][COUT];              // 4 KB (total 40960)

    const int t    = threadIdx.x;
    const int b    = blockIdx.x / NT;
    const int tile = blockIdx.x % NT;
    const int v0   = tile * BN;
    const int w    = t >> 6;
    const int l    = t & 63;
    const int wo   = (w & 1) * 64;       // wave o-offset
    const int wv   = (w >> 1) * 64;      // wave v-offset

    if constexpr (NORM)                  // per-batch inv-folded weights
        wF += (size_t)b * (KP1 * C / 32) * 8 * 64 * 8;

    // staging role: row sv = t>>1 (0..127), 64B half h = t&1
    const int sv = t >> 1;
    const int h  = t & 1;
    const int vS = v0 + sv;
    int idxS[KP1];
    {
        const int vc = (vS < V) ? vS : 0;
        idxS[0] = vc;
#pragma unroll
        for (int k = 1; k < KP1; ++k)
            idxS[k] = nbr[((size_t)b * V + vc) * 6 + (k - 1)];
    }

    // m (f16) for this thread's channel slice, both stage parities
    u16x8 mreg[2][4];
    if constexpr (NORM) {
        const u16* mp = mh + b * COUT;
#pragma unroll
        for (int sel = 0; sel < 2; ++sel)
#pragma unroll
            for (int j = 0; j < 4; ++j)
                mreg[sel][j] = *(const u16x8*)&mp[sel * 64 + h * 32 + j * 8];
    }

    // consumer vertices
    int vn[4]; bool ok[4];
#pragma unroll
    for (int n = 0; n < 4; ++n) {
        vn[n] = v0 + wv + n * 16 + (l & 15);
        ok[n] = vn[n] < V;
    }

    f32x4 acc[4][4];
#pragma unroll
    for (int m = 0; m < 4; ++m)
#pragma unroll
        for (int n = 0; n < 4; ++n) acc[m][n] = (f32x4)0.f;

    u16x8 g[2][4];    // gather regs: 64B per thread per stage, 2 sets (depth-2)
    f16x8 af[2][8];   // weight frags: (kc*4+m), double-buffered

    auto gload = [&](auto SC, u16x8 (&gr)[4]) {
        constexpr int S    = decltype(SC)::value;
        constexpr int k_   = (C == 64) ? S : (S >> 1);
        constexpr int off_ = (C == 64) ? 0 : (S & 1) * 64;
        const u16* p_ = &xin[((size_t)b * V + idxS[k_]) * C + off_ + h * 32];
#pragma unroll
        for (int j = 0; j < 4; ++j) gr[j] = *(const u16x8*)(p_ + j * 8);
    };
    auto aload = [&](auto SC, f16x8 (&ar)[8]) {
        constexpr int S = decltype(SC)::value;
#pragma unroll
        for (int kc = 0; kc < 2; ++kc)
#pragma unroll
            for (int m = 0; m < 4; ++m)
                ar[kc * 4 + m] =
                    *(const f16x8*)&wF[(((size_t)(2 * S + kc) * 8 + (wo >> 4) + m) * 64 + l) * 8];
    };
    auto store = [&](int bufi, u16x8 (&gr)[4], auto SC) {
        if constexpr (NORM) {
            constexpr int sel = decltype(SC)::value & 1;
#pragma unroll
            for (int j = 0; j < 4; ++j) relusub8(gr[j], mreg[sel][j]);
        }
#pragma unroll
        for (int j = 0; j < 4; ++j)
            *(u16x8*)&Xl[bufi][sv][h * 32 + j * 8] = gr[j];
    };

    // prologue: stage0 -> buf0; stage1 -> g[1]; af(0)
    gload(std::integral_constant<int, 0>{}, g[0]);
    if constexpr (NS > 1) gload(std::integral_constant<int, 1>{}, g[1]);
    aload(std::integral_constant<int, 0>{}, af[0]);
    store(0, g[0], std::integral_constant<int, 0>{});
    asm volatile("s_waitcnt lgkmcnt(0)" ::: "memory");
    __builtin_amdgcn_s_barrier();

    static_for<NS>([&](auto SC) {
        constexpr int s = decltype(SC)::value;
        // 1. bf reads from current buffer
        f16x8 bf[4][2];
#pragma unroll
        for (int n = 0; n < 4; ++n)
#pragma unroll
            for (int kc = 0; kc < 2; ++kc)
                bf[n][kc] = *(const f16x8*)&Xl[s & 1][wv + n * 16 + (l & 15)]
                                              [kc * 32 + (l >> 4) * 8];
        // 2. issue gather for stage s+2 (consumed by store at iter s+1)
        if constexpr (s + 2 < NS)
            gload(std::integral_constant<int, s + 2>{}, g[s & 1]);
        // 3. issue af for stage s+1
        if constexpr (s + 1 < NS)
            aload(std::integral_constant<int, s + 1>{}, af[(s + 1) & 1]);
        // 4. 32 MFMA
#pragma unroll
        for (int kc = 0; kc < 2; ++kc)
#pragma unroll
            for (int m = 0; m < 4; ++m)
#pragma unroll
                for (int n = 0; n < 4; ++n)
                    acc[m][n] = __builtin_amdgcn_mfma_f32_16x16x32_f16(af[s & 1][kc * 4 + m],
                                                                       bf[n][kc],
                                                                       acc[m][n], 0, 0, 0);
        // 5. write next stage to the other buffer (vmcnt stall lands after MFMAs)
        if constexpr (s + 1 < NS) {
            __builtin_amdgcn_sched_barrier(0);
            store((s + 1) & 1, g[(s + 1) & 1], std::integral_constant<int, s + 1>{});
            asm volatile("s_waitcnt lgkmcnt(0)" ::: "memory");
            __builtin_amdgcn_s_barrier();
        }
    });

    // D layout: o = wo + m*16 + (l>>4)*4 + q ; v = vn[n]
    if constexpr (OUTL == 0) {
        u16* po = (u16*)out_;
#pragma unroll
        for (int n = 0; n < 4; ++n) {
            if (ok[n]) {
#pragma unroll
                for (int m = 0; m < 4; ++m) {
                    const int o = wo + m * 16 + ((l >> 4) << 2);
                    u16x4 pk;
#pragma unroll
                    for (int q = 0; q < 4; ++q) pk[q] = f2h(acc[m][n][q] + bias[o + q]);
                    *(u16x4*)&po[((size_t)b * V + vn[n]) * COUT + o] = pk;
                }
            }
        }
    } else {
        float* po = (float*)out_;
#pragma unroll
        for (int m = 0; m < 4; ++m) {
            const int o = wo + m * 16 + ((l >> 4) << 2);
#pragma unroll
            for (int q = 0; q < 4; ++q) {
                const float bq = bias[o + q];
#pragma unroll
                for (int n = 0; n < 4; ++n)
                    if (ok[n]) po[((size_t)(b * COUT + o + q)) * V + vn[n]] = acc[m][n][q] + bq;
            }
        }
    }

    // fused instance-norm partials
#pragma unroll
    for (int m = 0; m < 4; ++m) {
        const int o = wo + m * 16 + ((l >> 4) << 2);
        float s[4], s2[4];
#pragma unroll
        for (int q = 0; q < 4; ++q) {
            const float bq = bias[o + q];
            float a = 0.f, aa = 0.f;
#pragma unroll
            for (int n = 0; n < 4; ++n) {
                if (ok[n]) {
                    const float val = acc[m][n][q] + bq;
                    a += val; aa += val * val;
                }
            }
            s[q] = a; s2[q] = aa;
        }
#pragma unroll
        for (int d = 1; d < 16; d <<= 1) {
#pragma unroll
            for (int q = 0; q < 4; ++q) {
                s[q]  += __shfl_xor(s[q],  d, 16);
                s2[q] += __shfl_xor(s2[q], d, 16);
            }
        }
        if ((l & 15) == 0) {
#pragma unroll
            for (int q = 0; q < 4; ++q)
                Sred[w][o + q] = make_float2(s[q], s2[q]);
        }
    }
    __syncthreads();
    if (t < COUT) {
        const int wlo = t >> 6;            // o-half -> waves wlo and wlo+2
        const float2 a = Sred[wlo][t];
        const float2 c = Sred[wlo + 2][t];
        P[((size_t)b * COUT + t) * NTP + tile] = make_float2(a.x + c.x, a.y + c.y);
    }
}

// ---- finalize fused partials: S[row] = (mean, rsqrt(var+eps)); mh = f16 mean ----
__global__ __launch_bounds__(256) void finalize_fused(const float2* __restrict__ P,
                                                      float2* __restrict__ S,
                                                      u16* __restrict__ mh) {
    const int row = blockIdx.x;       // B*COUT
    float s = 0.f, s2 = 0.f;
    for (int i = threadIdx.x; i < NT; i += 256) {
        const float2 p = P[(size_t)row * NTP + i];
        s += p.x; s2 += p.y;
    }
    __shared__ float2 red[256];
    red[threadIdx.x] = make_float2(s, s2);
    __syncthreads();
    for (int w = 128; w > 0; w >>= 1) {
        if (threadIdx.x < w) {
            red[threadIdx.x].x += red[threadIdx.x + w].x;
            red[threadIdx.x].y += red[threadIdx.x + w].y;
        }
        __syncthreads();
    }
    if (threadIdx.x == 0) {
        const float m = red[0].x / V;
        const float var = red[0].y / V - m * m;
        S[row] = make_float2(m, rsqrtf(var + EPS));
        if (mh) mh[row] = f2h(m);
    }
}

// ---- final (full tier): y2,y1raw vertex-major f16 -> out channel-major f32 ----
// out = relu((y2 - m2)*inv2 + inv1*relu(y1 - m1))
__global__ __launch_bounds__(256) void final_mix2(const u16* __restrict__ y2,
                                                  const u16* __restrict__ y1,
                                                  const float2* __restrict__ S1,
                                                  const float2* __restrict__ S2,
                                                  float* __restrict__ out) {
    __shared__ float ty[64][33], tx[64][33];
    const int t  = threadIdx.x;
    const int v0 = blockIdx.x * 64;
    const int o0 = blockIdx.y * 32;
    const int b  = blockIdx.z;
    const int jr = (t & 7) * 4;
    const int ir = t >> 3;             // 0..31
#pragma unroll
    for (int p = 0; p < 2; ++p) {
        const int i = ir + p * 32;
        const int v = v0 + i;
        if (v < V) {
            const size_t base = ((size_t)b * V + v) * COUT + o0 + jr;
            const u16x4 a = *(const u16x4*)&y2[base];
            const u16x4 c = *(const u16x4*)&y1[base];
#pragma unroll
            for (int q = 0; q < 4; ++q) {
                const float2 s1 = S1[b * COUT + o0 + jr + q];
                ty[i][jr + q] = h2f(a[q]);
                tx[i][jr + q] = s1.y * fmaxf(h2f(c[q]) - s1.x, 0.f);
            }
        }
    }
    __syncthreads();
    const int vl = t & 63, v = v0 + vl, oo0 = t >> 6;
    if (v < V) {
#pragma unroll
        for (int p = 0; p < 8; ++p) {
            const int oo = oo0 + p * 4;
            const int o  = o0 + oo;
            const float2 s = S2[b * COUT + o];
            out[((size_t)b * COUT + o) * V + v] =
                fmaxf((ty[vl][oo] - s.x) * s.y + tx[vl][oo], 0.f);
        }
    }
}

// ---- final (fallback tier): y2 f32 CM in place; y1raw f16 VM staged via LDS ----
__global__ __launch_bounds__(256) void final_mix(float* __restrict__ y,
                                                 const u16* __restrict__ y1,
                                                 const float2* __restrict__ S1,
                                                 const float2* __restrict__ S2) {
    __shared__ float tile[64][33];
    const int t  = threadIdx.x;
    const int v0 = blockIdx.x * 64;
    const int o0 = blockIdx.y * 32;
    const int b  = blockIdx.z;
    const int j  = t & 31;
    const int i0 = t >> 5;
    const float2 s1 = S1[b * COUT + o0 + j];
#pragma unroll
    for (int p = 0; p < 8; ++p) {
        const int i = i0 + p * 8;
        const int v = v0 + i;
        tile[i][j] = (v < V)
            ? s1.y * fmaxf(h2f(y1[((size_t)b * V + v) * COUT + o0 + j]) - s1.x, 0.f)
            : 0.f;
    }
    __syncthreads();
    const int vl  = t & 63;
    const int v   = v0 + vl;
    const int oo0 = t >> 6;
    if (v < V) {
#pragma unroll
        for (int p = 0; p < 8; ++p) {
            const int oo = oo0 + p * 4;
            const int o  = o0 + oo;
            const size_t idx = ((size_t)b * COUT + o) * V + v;
            const float2 s = S2[b * COUT + o];
            const float f = (y[idx] - s.x) * s.y + tile[vl][oo];
            y[idx] = fmaxf(f, 0.f);
        }
    }
}

extern "C" void kernel_launch(void* const* d_in, const int* in_sizes, int n_in,
                              void* d_out, int out_size, void* d_ws, size_t ws_size,
                              hipStream_t stream) {
    const float* fe  = (const float*)d_in[0];
    const int*   nbr = (const int*)d_in[1];
    const float* w1  = (const float*)d_in[2];
    const float* b1  = (const float*)d_in[3];
    const float* w2  = (const float*)d_in[4];
    const float* b2  = (const float*)d_in[5];
    float* outf = (float*)d_out;
    char*  ws   = (char*)d_ws;

    constexpr size_t wF1_b = (size_t)(KP1 * CIN  / 32) * 8 * 64 * 8 * 2;      // 112 KB
    constexpr size_t wF2_b = (size_t)B * (KP1 * COUT / 32) * 8 * 64 * 8 * 2;  // 896 KB (x4)
    constexpr size_t S_b   = (size_t)B * COUT * 8;
    constexpr size_t mh_b  = ((size_t)B * COUT * 2 + 255) & ~255ull;
    constexpr size_t Pf_b  = (size_t)B * COUT * NTP * 8;  // 1.6 MB
    constexpr size_t x1_b  = (size_t)B * V * COUT * 2;    // 51.2 MB
    constexpr size_t y2_b  = (size_t)B * V * COUT * 2;    // 51.2 MB
    constexpr size_t feT_b = (size_t)B * V * CIN * 2;     // 25.6 MB
    const size_t base = wF1_b + wF2_b + 2 * S_b + mh_b + Pf_b;

    // tiers: full (feT then y2 overlay in ext), t3 (feT in ext, f32-CM out),
    //        t4 (feT parked inside d_out until conv2 overwrites it)
    const bool full = (ws_size >= base + x1_b + y2_b);
    const bool t3   = (ws_size >= base + x1_b + feT_b);
    const bool t4   = (ws_size >= base + x1_b);
    if (!full && !t3 && !t4) return;

    size_t off = 0;
    u16*    wF1 = (u16*)(ws + off);    off += wF1_b;
    u16*    wF2 = (u16*)(ws + off);    off += wF2_b;
    float2* S1  = (float2*)(ws + off); off += S_b;
    float2* S2  = (float2*)(ws + off); off += S_b;
    u16*    mh1 = (u16*)(ws + off);    off += mh_b;
    float2* P   = (float2*)(ws + off); off += Pf_b;
    u16*    x1  = (u16*)(ws + off);    off += x1_b;   // raw y1 (f16, VM)
    u16*    ext = (u16*)(ws + off);    // feT and/or y2 region (full/t3)

    u16* feT = (full || t3) ? ext : (u16*)d_out;   // t4: park feT in d_out

    prep_wf<CIN><<<(KP1 * CIN / 32) * 8 * 64 / 256, 256, 0, stream>>>(w1, wF1);

    dim3 gt((V + 31) / 32, CIN / 32, B);
    transpose_fe<<<gt, 256, 0, stream>>>(fe, feT);

    conv_mfma<CIN, 0, 0><<<B * NT, 256, 0, stream>>>(feT, wF1, b1, nbr, nullptr, x1, P);
    finalize_fused<<<B * COUT, 256, 0, stream>>>(P, S1, mh1);

    // per-batch inv-folded conv2 weights (needs S1)
    dim3 gw((KP1 * COUT / 32) * 8 * 64 / 256, B);
    prep_wf_inv<<<gw, 256, 0, stream>>>(w2, S1, wF2);

    dim3 gf(NT64, COUT / 32, B);
    if (full) {
        u16* y2 = ext;   // overlays feT (dead after conv1)
        conv_mfma<COUT, 0, 1><<<B * NT, 256, 0, stream>>>(x1, wF2, b2, nbr, mh1, y2, P);
        finalize_fused<<<B * COUT, 256, 0, stream>>>(P, S2, nullptr);
        final_mix2<<<gf, 256, 0, stream>>>(y2, x1, S1, S2, outf);
    } else {
        conv_mfma<COUT, 1, 1><<<B * NT, 256, 0, stream>>>(x1, wF2, b2, nbr, mh1, outf, P);
        finalize_fused<<<B * COUT, 256, 0, stream>>>(P, S2, nullptr);
        final_mix<<<gf, 256, 0, stream>>>(outf, x1, S1, S2);
    }
}

// Round 16
// 219.946 us; speedup vs baseline: 1.4139x; 1.0196x over previous
//
#include <hip/hip_runtime.h>
#include <cstdint>
#include <cstddef>
#include <utility>

typedef unsigned short u16;
typedef u16 u16x8 __attribute__((ext_vector_type(8)));
typedef u16 u16x4 __attribute__((ext_vector_type(4)));
typedef _Float16 f16x8 __attribute__((ext_vector_type(8)));
typedef float f32x4 __attribute__((ext_vector_type(4)));

constexpr int B    = 4;
constexpr int CIN  = 64;
constexpr int COUT = 128;
constexpr int V    = 50000;
constexpr int KP1  = 7;
constexpr float EPS = 1e-5f;

constexpr int BN   = 128;                // vertices per conv block
constexpr int NT   = (V + BN - 1) / BN;  // 391
constexpr int NTP  = 392;                // padded tiles (grid 4*392 % 8 == 0)
constexpr int NT64 = (V + 63) / 64;      // 782 (final_mix tiles)

__device__ __forceinline__ u16 f2h(float f) {
    _Float16 h = (_Float16)f;
    return __builtin_bit_cast(u16, h);
}
__device__ __forceinline__ float h2f(u16 s) {
    return (float)__builtin_bit_cast(_Float16, s);
}

// packed f16: a = max(a - m, 0)  (native _Float16 vector ops -> v_pk_*)
__device__ __forceinline__ void relusub8(u16x8& a, const u16x8& m) {
    f16x8 af = __builtin_bit_cast(f16x8, a);
    f16x8 mf = __builtin_bit_cast(f16x8, m);
    f16x8 r = af - mf;
#pragma unroll
    for (int j = 0; j < 8; ++j)
        r[j] = (r[j] > (_Float16)0.f) ? r[j] : (_Float16)0.f;
    a = __builtin_bit_cast(u16x8, r);
}

template<int... Is, typename F>
__device__ __forceinline__ void static_for_impl(F&& f, std::integer_sequence<int, Is...>) {
    (f(std::integral_constant<int, Is>{}), ...);
}
template<int N, typename F>
__device__ __forceinline__ void static_for(F&& f) {
    static_for_impl(f, std::make_integer_sequence<int, N>{});
}

// ---- W -> fragment-ordered fp16: wF[ch][mfrag][lane][j] = W[o][r],
//      o = mfrag*16 + (lane&15), r = ch*32 + (lane>>4)*8 + j, r = k*C+c ----
template<int C>
__global__ __launch_bounds__(256) void prep_wf(const float* __restrict__ w,
                                               u16* __restrict__ wF) {
    constexpr int RCH = KP1 * C / 32;
    const int g = blockIdx.x * 256 + threadIdx.x;
    if (g >= RCH * 8 * 64) return;
    const int l  = g & 63;
    const int m  = (g >> 6) & 7;
    const int ch = g >> 9;
    const int k  = ch / (C / 32);
    const int c0 = (ch % (C / 32)) * 32;
    const int o  = m * 16 + (l & 15);
    u16x8 out;
#pragma unroll
    for (int j = 0; j < 8; ++j) {
        const int c = c0 + (l >> 4) * 8 + j;
        out[j] = f2h(w[((size_t)o * C + c) * KP1 + k]);
    }
    *(u16x8*)&wF[(size_t)g * 8] = out;
}

// ---- W2 * inv_c (per batch): wF2[b][...] = W2[o][c][k] * S1[b][c].inv ----
__global__ __launch_bounds__(256) void prep_wf_inv(const float* __restrict__ w,
                                                   const float2* __restrict__ S1,
                                                   u16* __restrict__ wF) {
    constexpr int C = COUT;
    constexpr int RCH = KP1 * C / 32;      // 28
    const int g  = blockIdx.x * 256 + threadIdx.x;
    const int bb = blockIdx.y;
    if (g >= RCH * 8 * 64) return;
    const int l  = g & 63;
    const int m  = (g >> 6) & 7;
    const int ch = g >> 9;
    const int k  = ch / (C / 32);
    const int c0 = (ch % (C / 32)) * 32;
    const int o  = m * 16 + (l & 15);
    u16x8 out;
#pragma unroll
    for (int j = 0; j < 8; ++j) {
        const int c = c0 + (l >> 4) * 8 + j;
        out[j] = f2h(w[((size_t)o * C + c) * KP1 + k] * S1[bb * COUT + c].y);
    }
    *(u16x8*)&wF[(size_t)bb * RCH * 8 * 64 * 8 + (size_t)g * 8] = out;
}

// ---- fe transpose: fe[b][c][v] (f32) -> feT[b][v][c] (f16) ----
__global__ __launch_bounds__(256) void transpose_fe(const float* __restrict__ fe,
                                                    u16* __restrict__ feT) {
    __shared__ u16 tile[32][33];
    const int t  = threadIdx.x;
    const int tx = t & 31, ty = t >> 5;           // 32 x 8
    const int v0 = blockIdx.x * 32;
    const int c0 = blockIdx.y * 32;
    const int b  = blockIdx.z;
#pragma unroll
    for (int p = 0; p < 4; ++p) {
        const int c = c0 + ty + p * 8;
        const int v = v0 + tx;
        if (v < V) tile[ty + p * 8][tx] = f2h(fe[((size_t)b * CIN + c) * V + v]);
    }
    __syncthreads();
#pragma unroll
    for (int p = 0; p < 4; ++p) {
        const int v = v0 + ty + p * 8;
        const int c = c0 + tx;
        if (v < V) feT[((size_t)b * V + v) * CIN + c] = tile[tx][ty + p * 8];
    }
}

// ---- MFMA gather-conv (round-8 structure): 64-channel stages, 2 LDS buffers,
//      reg-staged depth-2 gather pipeline, counted-wait barriers,
//      XCD batch-clustering swizzle (grid = B*NTP, %8==0).
// Decode: b = (i&7)>>1 (XCD pair under i%8 round-robin), tile interleaved.
// Block = 128o x 128v; waves 2x2, wave tile 64o x 64v; 32 MFMA per barrier.
// xin: vertex-major f16 [B][V][C] (raw y1 for conv2)
// OUTL: 0 = vertex-major f16 [B][V][COUT]; 1 = channel-major f32
// NORM: 1 = apply relu(x - m) at stage-write time (m = mh[b][c], f16);
//       weights are per-batch (inv-folded).
// Fuses instance-norm partial stats (sum, sumsq) into P.
template<int C, int OUTL, int NORM>
__global__ __launch_bounds__(256, 2) void conv_mfma(const u16* __restrict__ xin,
                                                    const u16* __restrict__ wF,
                                                    const float* __restrict__ bias,
                                                    const int*  __restrict__ nbr,
                                                    const u16*  __restrict__ mh,
                                                    void* __restrict__ out_,
                                                    float2* __restrict__ P) {
    constexpr int NS = KP1 * C / 64;     // 7 or 14 stages (64 ch each)
    __shared__ __align__(16) u16 Xl[2][BN][72];   // 36.9 KB; 144B rows
    __shared__ float2 Sred[4][COUT];              // 4 KB (total 40960)

    const int i    = blockIdx.x;
    const int b    = (i & 7) >> 1;               // XCD pair -> batch
    const int tile = ((i >> 3) << 1) | (i & 1);  // 0..391 (tile 391 = idle pad)
    const int v0   = tile * BN;
    const int t    = threadIdx.x;
    const int w    = t >> 6;
    const int l    = t & 63;
    const int wo   = (w & 1) * 64;       // wave o-offset
    const int wv   = (w >> 1) * 64;      // wave v-offset

    if constexpr (NORM)                  // per-batch inv-folded weights
        wF += (size_t)b * (KP1 * C / 32) * 8 * 64 * 8;

    // staging role: row sv = t>>1 (0..127), 64B half h = t&1
    const int sv = t >> 1;
    const int h  = t & 1;
    const int vS = v0 + sv;
    int idxS[KP1];
    {
        const int vc = (vS < V) ? vS : 0;
        idxS[0] = vc;
#pragma unroll
        for (int k = 1; k < KP1; ++k)
            idxS[k] = nbr[((size_t)b * V + vc) * 6 + (k - 1)];
    }

    // m (f16) for this thread's channel slice, both stage parities
    u16x8 mreg[2][4];
    if constexpr (NORM) {
        const u16* mp = mh + b * COUT;
#pragma unroll
        for (int sel = 0; sel < 2; ++sel)
#pragma unroll
            for (int j = 0; j < 4; ++j)
                mreg[sel][j] = *(const u16x8*)&mp[sel * 64 + h * 32 + j * 8];
    }

    // consumer vertices
    int vn[4]; bool ok[4];
#pragma unroll
    for (int n = 0; n < 4; ++n) {
        vn[n] = v0 + wv + n * 16 + (l & 15);
        ok[n] = vn[n] < V;
    }

    f32x4 acc[4][4];
#pragma unroll
    for (int m = 0; m < 4; ++m)
#pragma unroll
        for (int n = 0; n < 4; ++n) acc[m][n] = (f32x4)0.f;

    u16x8 g[2][4];    // gather regs: 64B per thread per stage, 2 sets (depth-2)
    f16x8 af[2][8];   // weight frags: (kc*4+m), double-buffered

    auto gload = [&](auto SC, u16x8 (&gr)[4]) {
        constexpr int S    = decltype(SC)::value;
        constexpr int k_   = (C == 64) ? S : (S >> 1);
        constexpr int off_ = (C == 64) ? 0 : (S & 1) * 64;
        const u16* p_ = &xin[((size_t)b * V + idxS[k_]) * C + off_ + h * 32];
#pragma unroll
        for (int j = 0; j < 4; ++j) gr[j] = *(const u16x8*)(p_ + j * 8);
    };
    auto aload = [&](auto SC, f16x8 (&ar)[8]) {
        constexpr int S = decltype(SC)::value;
#pragma unroll
        for (int kc = 0; kc < 2; ++kc)
#pragma unroll
            for (int m = 0; m < 4; ++m)
                ar[kc * 4 + m] =
                    *(const f16x8*)&wF[(((size_t)(2 * S + kc) * 8 + (wo >> 4) + m) * 64 + l) * 8];
    };
    auto store = [&](int bufi, u16x8 (&gr)[4], auto SC) {
        if constexpr (NORM) {
            constexpr int sel = decltype(SC)::value & 1;
#pragma unroll
            for (int j = 0; j < 4; ++j) relusub8(gr[j], mreg[sel][j]);
        }
#pragma unroll
        for (int j = 0; j < 4; ++j)
            *(u16x8*)&Xl[bufi][sv][h * 32 + j * 8] = gr[j];
    };

    // prologue: stage0 -> buf0; stage1 -> g[1]; af(0)
    gload(std::integral_constant<int, 0>{}, g[0]);
    if constexpr (NS > 1) gload(std::integral_constant<int, 1>{}, g[1]);
    aload(std::integral_constant<int, 0>{}, af[0]);
    store(0, g[0], std::integral_constant<int, 0>{});
    asm volatile("s_waitcnt lgkmcnt(0)" ::: "memory");
    __builtin_amdgcn_s_barrier();

    static_for<NS>([&](auto SC) {
        constexpr int s = decltype(SC)::value;
        // 1. bf reads from current buffer
        f16x8 bf[4][2];
#pragma unroll
        for (int n = 0; n < 4; ++n)
#pragma unroll
            for (int kc = 0; kc < 2; ++kc)
                bf[n][kc] = *(const f16x8*)&Xl[s & 1][wv + n * 16 + (l & 15)]
                                              [kc * 32 + (l >> 4) * 8];
        // 2. issue gather for stage s+2 (consumed by store at iter s+1)
        if constexpr (s + 2 < NS)
            gload(std::integral_constant<int, s + 2>{}, g[s & 1]);
        // 3. issue af for stage s+1
        if constexpr (s + 1 < NS)
            aload(std::integral_constant<int, s + 1>{}, af[(s + 1) & 1]);
        // 4. 32 MFMA
#pragma unroll
        for (int kc = 0; kc < 2; ++kc)
#pragma unroll
            for (int m = 0; m < 4; ++m)
#pragma unroll
                for (int n = 0; n < 4; ++n)
                    acc[m][n] = __builtin_amdgcn_mfma_f32_16x16x32_f16(af[s & 1][kc * 4 + m],
                                                                       bf[n][kc],
                                                                       acc[m][n], 0, 0, 0);
        // 5. write next stage to the other buffer (vmcnt stall lands after MFMAs)
        if constexpr (s + 1 < NS) {
            __builtin_amdgcn_sched_barrier(0);
            store((s + 1) & 1, g[(s + 1) & 1], std::integral_constant<int, s + 1>{});
            asm volatile("s_waitcnt lgkmcnt(0)" ::: "memory");
            __builtin_amdgcn_s_barrier();
        }
    });

    // D layout: o = wo + m*16 + (l>>4)*4 + q ; v = vn[n]
    if constexpr (OUTL == 0) {
        u16* po = (u16*)out_;
#pragma unroll
        for (int n = 0; n < 4; ++n) {
            if (ok[n]) {
#pragma unroll
                for (int m = 0; m < 4; ++m) {
                    const int o = wo + m * 16 + ((l >> 4) << 2);
                    u16x4 pk;
#pragma unroll
                    for (int q = 0; q < 4; ++q) pk[q] = f2h(acc[m][n][q] + bias[o + q]);
                    *(u16x4*)&po[((size_t)b * V + vn[n]) * COUT + o] = pk;
                }
            }
        }
    } else {
        float* po = (float*)out_;
#pragma unroll
        for (int m = 0; m < 4; ++m) {
            const int o = wo + m * 16 + ((l >> 4) << 2);
#pragma unroll
            for (int q = 0; q < 4; ++q) {
                const float bq = bias[o + q];
#pragma unroll
                for (int n = 0; n < 4; ++n)
                    if (ok[n]) po[((size_t)(b * COUT + o + q)) * V + vn[n]] = acc[m][n][q] + bq;
            }
        }
    }

    // fused instance-norm partials
#pragma unroll
    for (int m = 0; m < 4; ++m) {
        const int o = wo + m * 16 + ((l >> 4) << 2);
        float s[4], s2[4];
#pragma unroll
        for (int q = 0; q < 4; ++q) {
            const float bq = bias[o + q];
            float a = 0.f, aa = 0.f;
#pragma unroll
            for (int n = 0; n < 4; ++n) {
                if (ok[n]) {
                    const float val = acc[m][n][q] + bq;
                    a += val; aa += val * val;
                }
            }
            s[q] = a; s2[q] = aa;
        }
#pragma unroll
        for (int d = 1; d < 16; d <<= 1) {
#pragma unroll
            for (int q = 0; q < 4; ++q) {
                s[q]  += __shfl_xor(s[q],  d, 16);
                s2[q] += __shfl_xor(s2[q], d, 16);
            }
        }
        if ((l & 15) == 0) {
#pragma unroll
            for (int q = 0; q < 4; ++q)
                Sred[w][o + q] = make_float2(s[q], s2[q]);
        }
    }
    __syncthreads();
    if (t < COUT) {
        const int wlo = t >> 6;            // o-half -> waves wlo and wlo+2
        const float2 a = Sred[wlo][t];
        const float2 c = Sred[wlo + 2][t];
        P[((size_t)b * COUT + t) * NTP + tile] = make_float2(a.x + c.x, a.y + c.y);
    }
}

// ---- finalize fused partials: S[row] = (mean, rsqrt(var+eps)); mh = f16 mean ----
__global__ __launch_bounds__(256) void finalize_fused(const float2* __restrict__ P,
                                                      float2* __restrict__ S,
                                                      u16* __restrict__ mh) {
    const int row = blockIdx.x;       // B*COUT
    float s = 0.f, s2 = 0.f;
    for (int i = threadIdx.x; i < NT; i += 256) {
        const float2 p = P[(size_t)row * NTP + i];
        s += p.x; s2 += p.y;
    }
    __shared__ float2 red[256];
    red[threadIdx.x] = make_float2(s, s2);
    __syncthreads();
    for (int w = 128; w > 0; w >>= 1) {
        if (threadIdx.x < w) {
            red[threadIdx.x].x += red[threadIdx.x + w].x;
            red[threadIdx.x].y += red[threadIdx.x + w].y;
        }
        __syncthreads();
    }
    if (threadIdx.x == 0) {
        const float m = red[0].x / V;
        const float var = red[0].y / V - m * m;
        S[row] = make_float2(m, rsqrtf(var + EPS));
        if (mh) mh[row] = f2h(m);
    }
}

// ---- final (full tier): y2,y1raw vertex-major f16 -> out channel-major f32 ----
// out = relu((y2 - m2)*inv2 + inv1*relu(y1 - m1))
__global__ __launch_bounds__(256) void final_mix2(const u16* __restrict__ y2,
                                                  const u16* __restrict__ y1,
                                                  const float2* __restrict__ S1,
                                                  const float2* __restrict__ S2,
                                                  float* __restrict__ out) {
    __shared__ float ty[64][33], tx[64][33];
    const int t  = threadIdx.x;
    const int v0 = blockIdx.x * 64;
    const int o0 = blockIdx.y * 32;
    const int b  = blockIdx.z;
    const int jr = (t & 7) * 4;
    const int ir = t >> 3;             // 0..31
#pragma unroll
    for (int p = 0; p < 2; ++p) {
        const int i = ir + p * 32;
        const int v = v0 + i;
        if (v < V) {
            const size_t base = ((size_t)b * V + v) * COUT + o0 + jr;
            const u16x4 a = *(const u16x4*)&y2[base];
            const u16x4 c = *(const u16x4*)&y1[base];
#pragma unroll
            for (int q = 0; q < 4; ++q) {
                const float2 s1 = S1[b * COUT + o0 + jr + q];
                ty[i][jr + q] = h2f(a[q]);
                tx[i][jr + q] = s1.y * fmaxf(h2f(c[q]) - s1.x, 0.f);
            }
        }
    }
    __syncthreads();
    const int vl = t & 63, v = v0 + vl, oo0 = t >> 6;
    if (v < V) {
#pragma unroll
        for (int p = 0; p < 8; ++p) {
            const int oo = oo0 + p * 4;
            const int o  = o0 + oo;
            const float2 s = S2[b * COUT + o];
            out[((size_t)b * COUT + o) * V + v] =
                fmaxf((ty[vl][oo] - s.x) * s.y + tx[vl][oo], 0.f);
        }
    }
}

// ---- final (fallback tier): y2 f32 CM in place; y1raw f16 VM staged via LDS ----
__global__ __launch_bounds__(256) void final_mix(float* __restrict__ y,
                                                 const u16* __restrict__ y1,
                                                 const float2* __restrict__ S1,
                                                 const float2* __restrict__ S2) {
    __shared__ float tile[64][33];
    const int t  = threadIdx.x;
    const int v0 = blockIdx.x * 64;
    const int o0 = blockIdx.y * 32;
    const int b  = blockIdx.z;
    const int j  = t & 31;
    const int i0 = t >> 5;
    const float2 s1 = S1[b * COUT + o0 + j];
#pragma unroll
    for (int p = 0; p < 8; ++p) {
        const int i = i0 + p * 8;
        const int v = v0 + i;
        tile[i][j] = (v < V)
            ? s1.y * fmaxf(h2f(y1[((size_t)b * V + v) * COUT + o0 + j]) - s1.x, 0.f)
            : 0.f;
    }
    __syncthreads();
    const int vl  = t & 63;
    const int v   = v0 + vl;
    const int oo0 = t >> 6;
    if (v < V) {
#pragma unroll
        for (int p = 0; p < 8; ++p) {
            const int oo = oo0 + p * 4;
            const int o  = o0 + oo;
            const size_t idx = ((size_t)b * COUT + o) * V + v;
            const float2 s = S2[b * COUT + o];
            const float f = (y[idx] - s.x) * s.y + tile[vl][oo];
            y[idx] = fmaxf(f, 0.f);
        }
    }
}

extern "C" void kernel_launch(void* const* d_in, const int* in_sizes, int n_in,
                              void* d_out, int out_size, void* d_ws, size_t ws_size,
                              hipStream_t stream) {
    const float* fe  = (const float*)d_in[0];
    const int*   nbr = (const int*)d_in[1];
    const float* w1  = (const float*)d_in[2];
    const float* b1  = (const float*)d_in[3];
    const float* w2  = (const float*)d_in[4];
    const float* b2  = (const float*)d_in[5];
    float* outf = (float*)d_out;
    char*  ws   = (char*)d_ws;

    constexpr size_t wF1_b = (size_t)(KP1 * CIN  / 32) * 8 * 64 * 8 * 2;      // 112 KB
    constexpr size_t wF2_b = (size_t)B * (KP1 * COUT / 32) * 8 * 64 * 8 * 2;  // 896 KB (x4)
    constexpr size_t S_b   = (size_t)B * COUT * 8;
    constexpr size_t mh_b  = ((size_t)B * COUT * 2 + 255) & ~255ull;
    constexpr size_t Pf_b  = (size_t)B * COUT * NTP * 8;  // 1.6 MB
    constexpr size_t x1_b  = (size_t)B * V * COUT * 2;    // 51.2 MB
    constexpr size_t y2_b  = (size_t)B * V * COUT * 2;    // 51.2 MB
    constexpr size_t feT_b = (size_t)B * V * CIN * 2;     // 25.6 MB
    const size_t base = wF1_b + wF2_b + 2 * S_b + mh_b + Pf_b;

    // tiers: full (feT then y2 overlay in ext), t3 (feT in ext, f32-CM out),
    //        t4 (feT parked inside d_out until conv2 overwrites it)
    const bool full = (ws_size >= base + x1_b + y2_b);
    const bool t3   = (ws_size >= base + x1_b + feT_b);
    const bool t4   = (ws_size >= base + x1_b);
    if (!full && !t3 && !t4) return;

    size_t off = 0;
    u16*    wF1 = (u16*)(ws + off);    off += wF1_b;
    u16*    wF2 = (u16*)(ws + off);    off += wF2_b;
    float2* S1  = (float2*)(ws + off); off += S_b;
    float2* S2  = (float2*)(ws + off); off += S_b;
    u16*    mh1 = (u16*)(ws + off);    off += mh_b;
    float2* P   = (float2*)(ws + off); off += Pf_b;
    u16*    x1  = (u16*)(ws + off);    off += x1_b;   // raw y1 (f16, VM)
    u16*    ext = (u16*)(ws + off);    // feT and/or y2 region (full/t3)

    u16* feT = (full || t3) ? ext : (u16*)d_out;   // t4: park feT in d_out

    prep_wf<CIN><<<(KP1 * CIN / 32) * 8 * 64 / 256, 256, 0, stream>>>(w1, wF1);

    dim3 gt((V + 31) / 32, CIN / 32, B);
    transpose_fe<<<gt, 256, 0, stream>>>(fe, feT);

    conv_mfma<CIN, 0, 0><<<B * NTP, 256, 0, stream>>>(feT, wF1, b1, nbr, nullptr, x1, P);
    finalize_fused<<<B * COUT, 256, 0, stream>>>(P, S1, mh1);

    // per-batch inv-folded conv2 weights (needs S1)
    dim3 gw((KP1 * COUT / 32) * 8 * 64 / 256, B);
    prep_wf_inv<<<gw, 256, 0, stream>>>(w2, S1, wF2);

    dim3 gf(NT64, COUT / 32, B);
    if (full) {
        u16* y2 = ext;   // overlays feT (dead after conv1)
        conv_mfma<COUT, 0, 1><<<B * NTP, 256, 0, stream>>>(x1, wF2, b2, nbr, mh1, y2, P);
        finalize_fused<<<B * COUT, 256, 0, stream>>>(P, S2, nullptr);
        final_mix2<<<gf, 256, 0, stream>>>(y2, x1, S1, S2, outf);
    } else {
        conv_mfma<COUT, 1, 1><<<B * NTP, 256, 0, stream>>>(x1, wF2, b2, nbr, mh1, outf, P);
        finalize_fused<<<B * COUT, 256, 0, stream>>>(P, S2, nullptr);
        final_mix<<<gf, 256, 0, stream>>>(outf, x1, S1, S2);
    }
}